// Round 7
// baseline (301.141 us; speedup 1.0000x reference)
//
#include <hip/hip_runtime.h>
#include <stdint.h>

typedef __attribute__((ext_vector_type(4))) float f4;
typedef __attribute__((ext_vector_type(8))) short bf16x8;
typedef __attribute__((ext_vector_type(4))) unsigned short u16x4;
typedef unsigned short u16;

#define B_ 8
#define N_ 1024
#define C_ 768
#define NH 12
#define HD 64

__device__ __forceinline__ float bf2f(u16 v) {
  union { unsigned u; float f; } x; x.u = ((unsigned)v) << 16; return x.f;
}
__device__ __forceinline__ u16 f2bf(float f) {
  union { float f; unsigned u; } x; x.f = f;
  unsigned r = x.u + 0x7FFFu + ((x.u >> 16) & 1u);
  return (u16)(r >> 16);
}
// async global->LDS, 16B per lane
__device__ __forceinline__ void g2l16(const u16* g, const u16* l) {
  __builtin_amdgcn_global_load_lds(
      (const __attribute__((address_space(1))) void*)(uintptr_t)g,
      (__attribute__((address_space(3))) void*)(uint32_t)(uintptr_t)l,
      16, 0, 0);
}

// counted vmem waits (T4)
#define SW4()  asm volatile("s_waitcnt vmcnt(4)" ::: "memory")
#define SW3()  asm volatile("s_waitcnt vmcnt(3)" ::: "memory")
#define SW0()  asm volatile("s_waitcnt vmcnt(0)" ::: "memory")
// raw barrier + compile/IR fence (rule #18)
#define BARF()                              \
  do {                                      \
    __builtin_amdgcn_s_barrier();           \
    asm volatile("" ::: "memory");          \
    __builtin_amdgcn_sched_barrier(0);      \
  } while (0)

// ---------------- cvt: fp32 -> bf16, vectorized x4 ----------------
__global__ __launch_bounds__(256) void cvt_bf16(const float* __restrict__ s,
                                                u16* __restrict__ d, int n4) {
  int i = blockIdx.x * 256 + threadIdx.x;
  int stride = gridDim.x * 256;
  for (; i < n4; i += stride) {
    float4 v = ((const float4*)s)[i];
    u16x4 o;
    o.x = f2bf(v.x); o.y = f2bf(v.y); o.z = f2bf(v.z); o.w = f2bf(v.w);
    ((u16x4*)d)[i] = o;
  }
}

// ---------------- K0: LN stats ----------------
__global__ __launch_bounds__(256) void ln_stats(const float* __restrict__ y,
                                                float* __restrict__ mu,
                                                float* __restrict__ rs,
                                                int b0) {
  __shared__ float s1[4][64], s2[4][64];
  int t = threadIdx.x;
  int nl = t & 63, ch = t >> 6;
  int idx0 = b0 * N_ + blockIdx.x * 64;
  int b = idx0 >> 10, nb_ = idx0 & 1023;
  const float* p = y + (size_t)b * C_ * N_ + nb_ + nl;
  float s = 0.f, q = 0.f;
  int c0 = ch * 192;
  for (int c = c0; c < c0 + 192; ++c) {
    float v = p[(size_t)c * N_];
    s += v; q += v * v;
  }
  s1[ch][nl] = s; s2[ch][nl] = q;
  __syncthreads();
  if (t < 64) {
    float ts = s1[0][t] + s1[1][t] + s1[2][t] + s1[3][t];
    float tq = s2[0][t] + s2[1][t] + s2[2][t] + s2[3][t];
    float m = ts * (1.f / C_);
    float var = tq * (1.f / C_) - m * m;
    mu[idx0 + t] = m;
    rs[idx0 + t] = rsqrtf(fmaxf(var, 0.f) + 1e-5f);
  }
}

// ---------------- K1: transpose+normalize -> y2c bf16 ----------------
__global__ __launch_bounds__(256) void ln_apply(const float* __restrict__ y,
                                                const float* __restrict__ mu,
                                                const float* __restrict__ rs,
                                                const float* __restrict__ lg,
                                                const float* __restrict__ lb,
                                                u16* __restrict__ y2c,
                                                int b0) {
  __shared__ float tile[64][65];
  int t = threadIdx.x;
  int n0 = blockIdx.x * 64, c0 = blockIdx.y * 64;
  int bl = blockIdx.z, b = b0 + bl;
  int jc = (t & 15) * 4, ir = t >> 4;
  for (int r = 0; r < 4; ++r) {
    int i = ir + r * 16;
    float4 v = *(const float4*)(y + ((size_t)b * C_ + c0 + i) * N_ + n0 + jc);
    tile[i][jc] = v.x; tile[i][jc + 1] = v.y; tile[i][jc + 2] = v.z; tile[i][jc + 3] = v.w;
  }
  __syncthreads();
  for (int r = 0; r < 4; ++r) {
    int i = ir + r * 16;
    int n = n0 + i;
    float m = mu[b * N_ + n], rr = rs[b * N_ + n];
    float g0 = lg[c0 + jc],     b0f = lb[c0 + jc];
    float g1 = lg[c0 + jc + 1], b1f = lb[c0 + jc + 1];
    float g2 = lg[c0 + jc + 2], b2f = lb[c0 + jc + 2];
    float g3 = lg[c0 + jc + 3], b3f = lb[c0 + jc + 3];
    u16x4 o;
    o.x = f2bf((tile[jc][i] - m) * rr * g0 + b0f);
    o.y = f2bf((tile[jc + 1][i] - m) * rr * g1 + b1f);
    o.z = f2bf((tile[jc + 2][i] - m) * rr * g2 + b2f);
    o.w = f2bf((tile[jc + 3][i] - m) * rr * g3 + b3f);
    *(u16x4*)(y2c + ((size_t)bl * N_ + n) * C_ + c0 + jc) = o;
  }
}

// ---------------- K2: merged dual-A gated GEMM, 128x64 tiles -------------
// Occupancy-first redesign: per-wave acc = 64 regs (accx[4][2]+accy[4][2]),
// ~110 total -> launch_bounds(256,4) -> 4 waves/SIMD (2x the old 128x128
// dual-acc version, which sat at 248 regs = 2 waves/SIMD). Single 20KB LDS
// buffer, m97-proven serial loop; latency hidden by 16 waves/CU + 9
// blocks/CU of schedulable work (grid 64x36). One head per column-block.
__global__ __launch_bounds__(256, 4) void gemm_gate(
    const u16* __restrict__ xbc, const u16* __restrict__ y2c,
    const u16* __restrict__ qwb, const u16* __restrict__ kvwb,
    const float* __restrict__ qb_, const float* __restrict__ kvb_,
    u16* __restrict__ o_q, u16* __restrict__ o_k, u16* __restrict__ o_vT) {
  __shared__ u16 smem[10240];  // Ax[4096] Ay[4096] B[2048]; epilogue reuses 9216
  int t = threadIdx.x, l = t & 63;
  int quad = l >> 4, l15 = l & 15;
  int w = t >> 6, wm = w & 1, wn = w >> 1;
  int m0l = blockIdx.x * 128;
  int n0l = blockIdx.y * 64;

  const u16* wp; const float* bp; int sel, h0;
  if (n0l < C_) {
    wp = qwb + (size_t)n0l * C_; bp = qb_ + n0l; sel = 0; h0 = n0l >> 6;
  } else {
    int nk = n0l - C_;
    wp = kvwb + (size_t)nk * C_; bp = kvb_ + nk;
    sel = (nk < C_) ? 1 : 2;
    h0 = ((sel == 2) ? nk - C_ : nk) >> 6;
  }

  f4 accx[4][2], accy[4][2];
  for (int i = 0; i < 4; ++i)
    for (int j = 0; j < 2; ++j) {
      accx[i][j] = (f4){0.f, 0.f, 0.f, 0.f};
      accy[i][j] = (f4){0.f, 0.f, 0.f, 0.f};
    }

  int row = t >> 2, colb = (t & 3) * 8;
  const u16* gx = xbc + (size_t)(m0l + row) * C_ + colb;
  const u16* gy = y2c + (size_t)(m0l + row) * C_ + colb;
  const u16* gw = wp + (size_t)row * C_ + colb;   // row < 64 used for B

  for (int kk = 0; kk < C_; kk += 32) {
    __syncthreads();
    g2l16(gx + kk,           smem + t * 8);          // Ax rows 0-63
    g2l16(gx + kk + 64 * C_, smem + 2048 + t * 8);   // Ax rows 64-127
    g2l16(gy + kk,           smem + 4096 + t * 8);   // Ay rows 0-63
    g2l16(gy + kk + 64 * C_, smem + 6144 + t * 8);   // Ay rows 64-127
    g2l16(gw + kk,           smem + 8192 + t * 8);   // B 64 rows
    __syncthreads();
    bf16x8 bfr[2];
    for (int j = 0; j < 2; ++j)
      bfr[j] = *(const bf16x8*)&smem[8192 + (wn * 32 + j * 16 + l15) * 32 + quad * 8];
    {
      bf16x8 afx[4];
      for (int i = 0; i < 4; ++i)
        afx[i] = *(const bf16x8*)&smem[(wm * 64 + i * 16 + l15) * 32 + quad * 8];
      for (int i = 0; i < 4; ++i)
        for (int j = 0; j < 2; ++j)
          accx[i][j] = __builtin_amdgcn_mfma_f32_16x16x32_bf16(afx[i], bfr[j], accx[i][j], 0, 0, 0);
    }
    {
      bf16x8 afy[4];
      for (int i = 0; i < 4; ++i)
        afy[i] = *(const bf16x8*)&smem[4096 + (wm * 64 + i * 16 + l15) * 32 + quad * 8];
      for (int i = 0; i < 4; ++i)
        for (int j = 0; j < 2; ++j)
          accy[i][j] = __builtin_amdgcn_mfma_f32_16x16x32_bf16(afy[i], bfr[j], accy[i][j], 0, 0, 0);
    }
  }

  // epilogue: gate -> LDS tile -> cached 16-B stores
  __syncthreads();
  for (int j = 0; j < 2; ++j) {
    int cloc = wn * 32 + j * 16 + l15;
    float bias = bp[cloc];
    for (int i = 0; i < 4; ++i) {
      int rb0 = wm * 64 + i * 16 + quad * 4;
      for (int r = 0; r < 4; ++r) {
        int rloc = rb0 + r;
        float vx = accx[i][j][r] + bias;
        float vy = accy[i][j][r] + bias;
        float gg = 1.f / (1.f + __expf(-vy));
        float val = (sel == 0) ? vx * (1.f + gg) : gg * (vx + 1.f);
        u16 bv = f2bf(val);
        if (sel == 2) smem[cloc * 136 + rloc] = bv;   // v staged transposed [64][136]
        else          smem[rloc * 72 + cloc] = bv;    // q/k [128][72]
      }
    }
  }
  __syncthreads();
  {
    int bl = m0l >> 10, nbase = m0l & 1023;
    if (sel == 2) {
      int d = t >> 2, qc = t & 3;                    // 64 rows x 4 chunks of 32
      const u16* src = smem + d * 136 + qc * 32;
      u16* dst = o_vT + (size_t)((bl * NH + h0) * HD + d) * N_ + nbase + qc * 32;
      for (int c = 0; c < 4; ++c)
        *(bf16x8*)(dst + c * 8) = *(const bf16x8*)(src + c * 8);
    } else {
      int rr = t >> 1, hf = t & 1;                   // 128 rows x 2 chunks of 32
      const u16* src = smem + rr * 72 + hf * 32;
      int gml = m0l + rr;
      int bl2 = gml >> 10, n = gml & 1023;
      u16* dst = (sel == 0 ? o_q : o_k) +
                 (size_t)((bl2 * NH + h0) * N_ + n) * HD + hf * 32;
      for (int c = 0; c < 4; ++c)
        *(bf16x8*)(dst + c * 8) = *(const bf16x8*)(src + c * 8);
    }
  }
}

// ---------------- K3: fused attention (R6-exact) ----------------
__global__ __launch_bounds__(256) void attn(const u16* __restrict__ qoc,
                                            const u16* __restrict__ koc,
                                            const u16* __restrict__ vTc,
                                            u16* __restrict__ aoc) {
  __shared__ u16 Qs[4096], Ks[8192], Vs[8192];
  __shared__ u16 Ps[64 * 72];
  int t = threadIdx.x, l = t & 63, w = t >> 6;
  int quad = l >> 4, l15 = l & 15;
  int bhl = blockIdx.y;
  int bl = bhl / NH, h = bhl % NH;
  int q0 = blockIdx.x * 64;
  int sr = t >> 3;                       // staging row (0..31, +32 second half)
  int swo = ((t & 7) ^ (sr & 7)) * 8;    // swizzled source chunk offset (u16)
  const u16* qbp = qoc + ((size_t)bhl * N_ + q0) * HD;
  const u16* kb = koc + (size_t)bhl * N_ * HD;
  const u16* vb = vTc + (size_t)bhl * HD * N_;

#define STAGE_KV(OFF, key0)                                                   \
  do {                                                                        \
    g2l16(kb + (size_t)((key0) + sr) * HD + swo,      Ks + (OFF) + t * 8);    \
    g2l16(kb + (size_t)((key0) + 32 + sr) * HD + swo, Ks + (OFF) + 2048 + t * 8); \
    g2l16(vb + (size_t)sr * N_ + (key0) + swo,        Vs + (OFF) + t * 8);    \
    g2l16(vb + (size_t)(32 + sr) * N_ + (key0) + swo, Vs + (OFF) + 2048 + t * 8); \
  } while (0)

  g2l16(qbp + sr * HD + swo,        Qs + t * 8);
  g2l16(qbp + (32 + sr) * HD + swo, Qs + 2048 + t * 8);
  STAGE_KV(0, 0);
  STAGE_KV(4096, 64);
  SW4();   // Q(2) + KV0(4) done; KV1's 4 in flight
  BARF();

  int sA = (quad ^ (l15 & 7)) * 8;  // swizzled slot, contraction chunks 0-3
  int sB = sA ^ 32;                 // chunks 4-7
  bf16x8 aq0 = *(const bf16x8*)&Qs[(w * 16 + l15) * 64 + sA];
  bf16x8 aq1 = *(const bf16x8*)&Qs[(w * 16 + l15) * 64 + sB];
  f4 o[4];
  for (int i = 0; i < 4; ++i) o[i] = (f4){0.f, 0.f, 0.f, 0.f};
  f4 ls = (f4){0.f, 0.f, 0.f, 0.f};
  bf16x8 ones;
  for (int i = 0; i < 8; ++i) ones[i] = (short)0x3F80;  // bf16 1.0

#define TILE_STEP(KOFF)                                                       \
  do {                                                                        \
    f4 s_[4];                                                                 \
    __builtin_amdgcn_s_setprio(1);                                            \
    for (int ni = 0; ni < 4; ++ni) {                                          \
      bf16x8 b0v = *(const bf16x8*)&Ks[(KOFF) + (ni * 16 + l15) * 64 + sA];   \
      bf16x8 b1v = *(const bf16x8*)&Ks[(KOFF) + (ni * 16 + l15) * 64 + sB];   \
      f4 z = (f4){0.f, 0.f, 0.f, 0.f};                                        \
      z = __builtin_amdgcn_mfma_f32_16x16x32_bf16(aq0, b0v, z, 0, 0, 0);      \
      z = __builtin_amdgcn_mfma_f32_16x16x32_bf16(aq1, b1v, z, 0, 0, 0);      \
      s_[ni] = z;                                                             \
    }                                                                         \
    __builtin_amdgcn_s_setprio(0);                                            \
    for (int ni = 0; ni < 4; ++ni)                                            \
      for (int r = 0; r < 4; ++r)                                             \
        Ps[(w * 16 + quad * 4 + r) * 72 + ni * 16 + l15] =                    \
            f2bf(__expf(s_[ni][r] * 0.125f));                                 \
    bf16x8 ap0 = *(const bf16x8*)&Ps[(w * 16 + l15) * 72 + quad * 8];         \
    bf16x8 ap1 = *(const bf16x8*)&Ps[(w * 16 + l15) * 72 + 32 + quad * 8];    \
    __builtin_amdgcn_s_setprio(1);                                            \
    for (int ni = 0; ni < 4; ++ni) {                                          \
      bf16x8 b0v = *(const bf16x8*)&Vs[(KOFF) + (ni * 16 + l15) * 64 + sA];   \
      bf16x8 b1v = *(const bf16x8*)&Vs[(KOFF) + (ni * 16 + l15) * 64 + sB];   \
      o[ni] = __builtin_amdgcn_mfma_f32_16x16x32_bf16(ap0, b0v, o[ni], 0, 0, 0); \
      o[ni] = __builtin_amdgcn_mfma_f32_16x16x32_bf16(ap1, b1v, o[ni], 0, 0, 0); \
    }                                                                         \
    ls = __builtin_amdgcn_mfma_f32_16x16x32_bf16(ap0, ones, ls, 0, 0, 0);     \
    ls = __builtin_amdgcn_mfma_f32_16x16x32_bf16(ap1, ones, ls, 0, 0, 0);     \
    __builtin_amdgcn_s_setprio(0);                                            \
  } while (0)

  for (int kt = 0; kt < 16; kt += 2) {
    TILE_STEP(0);
    BARF();                                   // done reading KV half 0
    if (kt + 2 < 16) { STAGE_KV(0, (kt + 2) * 64); SW4(); } else { SW0(); }
    BARF();                                   // KV half 1 visible
    TILE_STEP(4096);
    BARF();                                   // done reading KV half 1
    if (kt + 3 < 16) { STAGE_KV(4096, (kt + 3) * 64); SW4(); } else { SW0(); }
    BARF();                                   // KV half 0 visible
  }
#undef TILE_STEP
#undef STAGE_KV

  for (int ni = 0; ni < 4; ++ni)
    for (int r = 0; r < 4; ++r)
      Ps[(w * 16 + quad * 4 + r) * 72 + ni * 16 + l15] =
          f2bf(o[ni][r] / ls[r]);
  __syncthreads();
  {
    int rr = t >> 2, cc = t & 3;
    int n = q0 + rr;
    const u16* src = Ps + rr * 72 + cc * 16;
    u16* dst = aoc + ((size_t)bl * N_ + n) * C_ + h * HD + cc * 16;
    *(bf16x8*)dst = *(const bf16x8*)src;
    *(bf16x8*)(dst + 8) = *(const bf16x8*)(src + 8);
  }
}

// ---------------- K4: output projection GEMM, single-barrier depth-3 -----
__global__ __launch_bounds__(256, 2) void gemm_proj(const u16* __restrict__ aoc,
                                                    const u16* __restrict__ pwb,
                                                    const float* __restrict__ bias,
                                                    float* __restrict__ out,
                                                    int b0) {
  __shared__ u16 smem[18432];  // 3 bufs x (A 4096 + B 2048)
  int t = threadIdx.x, l = t & 63;
  int quad = l >> 4, l15 = l & 15;
  int w = t >> 6, wm = w & 1, wn = w >> 1;
  int m0l = blockIdx.x * 128, n0 = blockIdx.y * 64;
  f4 acc[4][2];
  for (int i = 0; i < 4; ++i)
    for (int j = 0; j < 2; ++j) acc[i][j] = (f4){0.f, 0.f, 0.f, 0.f};
  int row = t >> 2;
  int colS = (((t & 3) ^ (row & 3)) * 8);
  const u16* ga = aoc + (size_t)(m0l + row) * C_ + colS;
  const u16* gw = pwb + (size_t)(n0 + row) * C_ + colS;
  int rsl = (quad ^ (l15 & 3)) * 8;

#define STAGE_P(OFF, kk)                                   \
  do {                                                     \
    u16* p_ = smem + (OFF);                                \
    g2l16(ga + (kk),           p_ + t * 8);                \
    g2l16(ga + (kk) + 64 * C_, p_ + 2048 + t * 8);         \
    g2l16(gw + (kk),           p_ + 4096 + t * 8);         \
  } while (0)

#define COMPUTE_P(OFF)                                                        \
  do {                                                                        \
    const u16* base = smem + (OFF);                                           \
    bf16x8 af[4], bfr[2];                                                     \
    for (int i = 0; i < 4; ++i)                                               \
      af[i] = *(const bf16x8*)&base[(wm * 64 + i * 16 + l15) * 32 + rsl];     \
    for (int j = 0; j < 2; ++j)                                               \
      bfr[j] = *(const bf16x8*)&base[4096 + (wn * 32 + j * 16 + l15) * 32 + rsl]; \
    for (int i = 0; i < 4; ++i)                                               \
      for (int j = 0; j < 2; ++j)                                             \
        acc[i][j] = __builtin_amdgcn_mfma_f32_16x16x32_bf16(af[i], bfr[j], acc[i][j], 0, 0, 0); \
  } while (0)

#define STEP_P(i, OFFC, OFFS)                                 \
  do {                                                        \
    if ((i) <= 21) STAGE_P(OFFS, ((i) + 2) * 32);             \
    COMPUTE_P(OFFC);                                          \
    if ((i) <= 21)      SW3();                                \
    else if ((i) == 22) SW0();                                \
    BARF();                                                   \
  } while (0)

  STAGE_P(0, 0);
  STAGE_P(6144, 32);
  SW3();
  BARF();
  for (int n = 0; n < 24; n += 3) {
    STEP_P(n,     0,     12288);
    STEP_P(n + 1, 6144,  0);
    STEP_P(n + 2, 12288, 6144);
  }
#undef STEP_P
#undef STAGE_P
#undef COMPUTE_P

  for (int j = 0; j < 2; ++j) {
    int gcol = n0 + wn * 32 + j * 16 + l15;
    float bv = bias[gcol];
    for (int i = 0; i < 4; ++i) {
      int rbase = m0l + wm * 64 + i * 16 + quad * 4;
      for (int r = 0; r < 4; ++r)
        __builtin_nontemporal_store(acc[i][j][r] + bv,
                                    &out[(size_t)(b0 * N_ + rbase + r) * C_ + gcol]);
    }
  }
}

extern "C" void kernel_launch(void* const* d_in, const int* in_sizes, int n_in,
                              void* d_out, int out_size, void* d_ws, size_t ws_size,
                              hipStream_t stream) {
  const float* x   = (const float*)d_in[0];
  const float* y   = (const float*)d_in[1];
  const float* qw  = (const float*)d_in[2];
  const float* qb  = (const float*)d_in[3];
  const float* kvw = (const float*)d_in[4];
  const float* kvb = (const float*)d_in[5];
  const float* pw  = (const float*)d_in[6];
  const float* pb  = (const float*)d_in[7];
  const float* lg  = (const float*)d_in[8];
  const float* lb  = (const float*)d_in[9];

  char* ws = (char*)d_ws;
  float* mu = (float*)(ws);
  float* rs = (float*)(ws + 32768);
  u16* qwb  = (u16*)(ws + 65536);
  u16* kvwb = (u16*)(ws + 1245184);
  u16* pwb  = (u16*)(ws + 3604480);
  const size_t BASE2 = 4784128;
  const size_t PER_B = 1572864;

  int nb = 1;
  for (int c = 8; c >= 1; c >>= 1) {
    if (BASE2 + 5 * (size_t)c * PER_B <= ws_size) { nb = c; break; }
  }
  u16* xbc = (u16*)(ws + BASE2);
  u16* y2c = (u16*)(ws + BASE2 + (size_t)nb * PER_B);
  u16* qoc = (u16*)(ws + BASE2 + 2 * (size_t)nb * PER_B);
  u16* koc = (u16*)(ws + BASE2 + 3 * (size_t)nb * PER_B);
  u16* vTc = (u16*)(ws + BASE2 + 4 * (size_t)nb * PER_B);
  u16* aoc = xbc;

  cvt_bf16<<<dim3(576), dim3(256), 0, stream>>>(qw, qwb, 147456);
  cvt_bf16<<<dim3(1152), dim3(256), 0, stream>>>(kvw, kvwb, 294912);
  cvt_bf16<<<dim3(576), dim3(256), 0, stream>>>(pw, pwb, 147456);

  for (int b0 = 0; b0 < B_; b0 += nb) {
    cvt_bf16<<<dim3(768 * nb), dim3(256), 0, stream>>>(
        x + (size_t)b0 * N_ * C_, xbc, nb * 196608);
    ln_stats<<<dim3(16 * nb), dim3(256), 0, stream>>>(y, mu, rs, b0);
    ln_apply<<<dim3(16, 12, nb), dim3(256), 0, stream>>>(y, mu, rs, lg, lb, y2c, b0);
    gemm_gate<<<dim3(8 * nb, 36), dim3(256), 0, stream>>>(xbc, y2c, qwb, kvwb,
                                                          qb, kvb, qoc, koc, vTc);
    attn<<<dim3(16, 12 * nb), dim3(256), 0, stream>>>(qoc, koc, vTc, aoc);
    gemm_proj<<<dim3(8 * nb, 12), dim3(256), 0, stream>>>(aoc, pwb, pb, (float*)d_out, b0);
  }
}

// Round 8
// 284.748 us; speedup vs baseline: 1.0576x; 1.0576x over previous
//
#include <hip/hip_runtime.h>
#include <stdint.h>

typedef __attribute__((ext_vector_type(4))) float f4;
typedef __attribute__((ext_vector_type(8))) short bf16x8;
typedef __attribute__((ext_vector_type(4))) unsigned short u16x4;
typedef unsigned short u16;

#define B_ 8
#define N_ 1024
#define C_ 768
#define NH 12
#define HD 64

__device__ __forceinline__ float bf2f(u16 v) {
  union { unsigned u; float f; } x; x.u = ((unsigned)v) << 16; return x.f;
}
__device__ __forceinline__ u16 f2bf(float f) {
  union { float f; unsigned u; } x; x.f = f;
  unsigned r = x.u + 0x7FFFu + ((x.u >> 16) & 1u);
  return (u16)(r >> 16);
}
// async global->LDS, 16B per lane
__device__ __forceinline__ void g2l16(const u16* g, const u16* l) {
  __builtin_amdgcn_global_load_lds(
      (const __attribute__((address_space(1))) void*)(uintptr_t)g,
      (__attribute__((address_space(3))) void*)(uint32_t)(uintptr_t)l,
      16, 0, 0);
}

// counted vmem waits (T4): never drain to 0 in the main loop
#define SW12() asm volatile("s_waitcnt vmcnt(12)" ::: "memory")
#define SW6()  asm volatile("s_waitcnt vmcnt(6)" ::: "memory")
#define SW4()  asm volatile("s_waitcnt vmcnt(4)" ::: "memory")
#define SW3()  asm volatile("s_waitcnt vmcnt(3)" ::: "memory")
#define SW0()  asm volatile("s_waitcnt vmcnt(0)" ::: "memory")
// raw barrier + compile/IR fence (rule #18)
#define BARF()                              \
  do {                                      \
    __builtin_amdgcn_s_barrier();           \
    asm volatile("" ::: "memory");          \
    __builtin_amdgcn_sched_barrier(0);      \
  } while (0)

// ---------------- cvt: fp32 -> bf16, vectorized x4 ----------------
__global__ __launch_bounds__(256) void cvt_bf16(const float* __restrict__ s,
                                                u16* __restrict__ d, int n4) {
  int i = blockIdx.x * 256 + threadIdx.x;
  int stride = gridDim.x * 256;
  for (; i < n4; i += stride) {
    float4 v = ((const float4*)s)[i];
    u16x4 o;
    o.x = f2bf(v.x); o.y = f2bf(v.y); o.z = f2bf(v.z); o.w = f2bf(v.w);
    ((u16x4*)d)[i] = o;
  }
}

// ---------------- K0: LN stats ----------------
__global__ __launch_bounds__(256) void ln_stats(const float* __restrict__ y,
                                                float* __restrict__ mu,
                                                float* __restrict__ rs,
                                                int b0) {
  __shared__ float s1[4][64], s2[4][64];
  int t = threadIdx.x;
  int nl = t & 63, ch = t >> 6;
  int idx0 = b0 * N_ + blockIdx.x * 64;
  int b = idx0 >> 10, nb_ = idx0 & 1023;
  const float* p = y + (size_t)b * C_ * N_ + nb_ + nl;
  float s = 0.f, q = 0.f;
  int c0 = ch * 192;
  for (int c = c0; c < c0 + 192; ++c) {
    float v = p[(size_t)c * N_];
    s += v; q += v * v;
  }
  s1[ch][nl] = s; s2[ch][nl] = q;
  __syncthreads();
  if (t < 64) {
    float ts = s1[0][t] + s1[1][t] + s1[2][t] + s1[3][t];
    float tq = s2[0][t] + s2[1][t] + s2[2][t] + s2[3][t];
    float m = ts * (1.f / C_);
    float var = tq * (1.f / C_) - m * m;
    mu[idx0 + t] = m;
    rs[idx0 + t] = rsqrtf(fmaxf(var, 0.f) + 1e-5f);
  }
}

// ---------------- K1: transpose+normalize -> y2c bf16 ----------------
__global__ __launch_bounds__(256) void ln_apply(const float* __restrict__ y,
                                                const float* __restrict__ mu,
                                                const float* __restrict__ rs,
                                                const float* __restrict__ lg,
                                                const float* __restrict__ lb,
                                                u16* __restrict__ y2c,
                                                int b0) {
  __shared__ float tile[64][65];
  int t = threadIdx.x;
  int n0 = blockIdx.x * 64, c0 = blockIdx.y * 64;
  int bl = blockIdx.z, b = b0 + bl;
  int jc = (t & 15) * 4, ir = t >> 4;
  for (int r = 0; r < 4; ++r) {
    int i = ir + r * 16;
    float4 v = *(const float4*)(y + ((size_t)b * C_ + c0 + i) * N_ + n0 + jc);
    tile[i][jc] = v.x; tile[i][jc + 1] = v.y; tile[i][jc + 2] = v.z; tile[i][jc + 3] = v.w;
  }
  __syncthreads();
  for (int r = 0; r < 4; ++r) {
    int i = ir + r * 16;
    int n = n0 + i;
    float m = mu[b * N_ + n], rr = rs[b * N_ + n];
    float g0 = lg[c0 + jc],     b0f = lb[c0 + jc];
    float g1 = lg[c0 + jc + 1], b1f = lb[c0 + jc + 1];
    float g2 = lg[c0 + jc + 2], b2f = lb[c0 + jc + 2];
    float g3 = lg[c0 + jc + 3], b3f = lb[c0 + jc + 3];
    u16x4 o;
    o.x = f2bf((tile[jc][i] - m) * rr * g0 + b0f);
    o.y = f2bf((tile[jc + 1][i] - m) * rr * g1 + b1f);
    o.z = f2bf((tile[jc + 2][i] - m) * rr * g2 + b2f);
    o.w = f2bf((tile[jc + 3][i] - m) * rr * g3 + b3f);
    *(u16x4*)(y2c + ((size_t)bl * N_ + n) * C_ + c0 + jc) = o;
  }
}

// ---------------- K2: merged dual-A gated GEMM (R5-exact, best: 90us) ----
// Depth-3 pipeline, counted vmcnt(12), XOR-swizzled LDS, 128x128 tiles.
__global__ __launch_bounds__(256, 2) void gemm_gate(
    const u16* __restrict__ xbc, const u16* __restrict__ y2c,
    const u16* __restrict__ qwb, const u16* __restrict__ kvwb,
    const float* __restrict__ qb_, const float* __restrict__ kvb_,
    u16* __restrict__ o_q, u16* __restrict__ o_k, u16* __restrict__ o_vT) {
  __shared__ u16 smem[36864];  // 3 bufs x 12288 u16 (72 KiB); epilogue reuses front
  int t = threadIdx.x, l = t & 63;
  int quad = l >> 4, l15 = l & 15;
  int w = t >> 6, wm = w & 1, wn = w >> 1;
  int m0l = blockIdx.x * 128;
  int n0l = blockIdx.y * 128;

  const u16* wp; const float* bp; int sel, h0;
  if (n0l < C_) {
    wp = qwb + (size_t)n0l * C_; bp = qb_ + n0l; sel = 0; h0 = n0l >> 6;
  } else {
    int nk = n0l - C_;
    wp = kvwb + (size_t)nk * C_; bp = kvb_ + nk;
    sel = (nk < C_) ? 1 : 2;
    h0 = ((sel == 2) ? nk - C_ : nk) >> 6;
  }

  f4 accx[4][4], accy[4][4];
  for (int i = 0; i < 4; ++i)
    for (int j = 0; j < 4; ++j) {
      accx[i][j] = (f4){0.f, 0.f, 0.f, 0.f};
      accy[i][j] = (f4){0.f, 0.f, 0.f, 0.f};
    }

  int row = t >> 2;
  int colS = (((t & 3) ^ (row & 3)) * 8);   // pre-swizzled source chunk
  const u16* gx = xbc + (size_t)(m0l + row) * C_ + colS;
  const u16* gy = y2c + (size_t)(m0l + row) * C_ + colS;
  const u16* gw = wp + (size_t)row * C_ + colS;
  int rsl = (quad ^ (l15 & 3)) * 8;         // swizzled read slot (u16)

#define STAGE_G(OFF, kk)                                   \
  do {                                                     \
    u16* p_ = smem + (OFF);                                \
    g2l16(gx + (kk),           p_ + t * 8);                \
    g2l16(gx + (kk) + 64 * C_, p_ + 2048 + t * 8);         \
    g2l16(gy + (kk),           p_ + 4096 + t * 8);         \
    g2l16(gy + (kk) + 64 * C_, p_ + 6144 + t * 8);         \
    g2l16(gw + (kk),           p_ + 8192 + t * 8);         \
    g2l16(gw + (kk) + 64 * C_, p_ + 10240 + t * 8);        \
  } while (0)

#define COMPUTE_G(OFF)                                                        \
  do {                                                                        \
    const u16* base = smem + (OFF);                                           \
    bf16x8 afx[4], afy[4], bfr[4];                                            \
    for (int i = 0; i < 4; ++i) {                                             \
      int ra = (wm * 64 + i * 16 + l15) * 32 + rsl;                           \
      afx[i] = *(const bf16x8*)&base[ra];                                     \
      afy[i] = *(const bf16x8*)&base[4096 + ra];                              \
      int rb = (wn * 64 + i * 16 + l15) * 32 + rsl;                           \
      bfr[i] = *(const bf16x8*)&base[8192 + rb];                              \
    }                                                                         \
    for (int i = 0; i < 4; ++i)                                               \
      for (int j = 0; j < 4; ++j) {                                           \
        accx[i][j] = __builtin_amdgcn_mfma_f32_16x16x32_bf16(afx[i], bfr[j], accx[i][j], 0, 0, 0); \
        accy[i][j] = __builtin_amdgcn_mfma_f32_16x16x32_bf16(afy[i], bfr[j], accy[i][j], 0, 0, 0); \
      }                                                                       \
  } while (0)

#define STEP_G(i, OFF)                                        \
  do {                                                        \
    COMPUTE_G(OFF);                                           \
    BARF();                                                   \
    if ((i) < 21)      { STAGE_G(OFF, ((i) + 3) * 32); SW12(); } \
    else if ((i) == 21) SW6();                                \
    else if ((i) == 22) SW0();                                \
    BARF();                                                   \
  } while (0)

  STAGE_G(0, 0);
  STAGE_G(12288, 32);
  STAGE_G(24576, 64);
  SW12();   // tile0 done (tiles 1,2 in flight)
  BARF();
#pragma unroll
  for (int n = 0; n < 24; n += 3) {
    STEP_G(n, 0);
    STEP_G(n + 1, 12288);
    STEP_G(n + 2, 24576);
  }
#undef STEP_G
#undef STAGE_G
#undef COMPUTE_G

  // epilogue: gate -> LDS tile -> cached 16-B stores
  const int PITCH = 136;
  for (int j = 0; j < 4; ++j) {
    int cloc = wn * 64 + j * 16 + l15;
    float bias = bp[cloc];
    for (int i = 0; i < 4; ++i) {
      int rb0 = wm * 64 + i * 16 + quad * 4;
      for (int r = 0; r < 4; ++r) {
        int rloc = rb0 + r;
        float vx = accx[i][j][r] + bias;
        float vy = accy[i][j][r] + bias;
        float gg = 1.f / (1.f + __expf(-vy));
        float val = (sel == 0) ? vx * (1.f + gg) : gg * (vx + 1.f);
        u16 bv = f2bf(val);
        if (sel == 2) smem[cloc * PITCH + rloc] = bv;   // v staged transposed
        else          smem[rloc * PITCH + cloc] = bv;
      }
    }
  }
  __syncthreads();
  {
    int rr = t >> 1, hh = t & 1;
    const u16* src = smem + rr * PITCH + hh * 64;
    u16* dst;
    if (sel == 2) {
      int h = h0 + (rr >> 6), d = rr & 63;
      int bl = m0l >> 10, nbase = m0l & 1023;
      dst = o_vT + (size_t)((bl * NH + h) * HD + d) * N_ + nbase + hh * 64;
    } else {
      int gml = m0l + rr;
      int bl = gml >> 10, n = gml & 1023;
      int h = h0 + hh;
      dst = (sel == 0 ? o_q : o_k) + (size_t)((bl * NH + h) * N_ + n) * HD;
    }
    for (int c = 0; c < 8; ++c) {
      bf16x8 v = *(const bf16x8*)(src + c * 8);
      *(bf16x8*)(dst + c * 8) = v;
    }
  }
}

// ---------------- K3: fused attention, Q-tile 128 ------------------------
// Each block handles 128 q-rows (wave w owns two 16-row groups: w*16 and
// 64+w*16). K/V staged once per 128 q-rows (was per 64) -> half the KV
// staging traffic and half the barriers per q-row; K/V fragments shared
// across both row-groups. LDS 66KB -> 2 blocks/CU.
__global__ __launch_bounds__(256) void attn(const u16* __restrict__ qoc,
                                            const u16* __restrict__ koc,
                                            const u16* __restrict__ vTc,
                                            u16* __restrict__ aoc) {
  __shared__ u16 Qs[8192], Ks[8192], Vs[8192];
  __shared__ u16 Ps[128 * 72];
  int t = threadIdx.x, l = t & 63, w = t >> 6;
  int quad = l >> 4, l15 = l & 15;
  int bhl = blockIdx.y;
  int bl = bhl / NH, h = bhl % NH;
  int q0 = blockIdx.x * 128;
  int sr = t >> 3;                       // staging row (0..31 per 4KB chunk)
  int swo = ((t & 7) ^ (sr & 7)) * 8;    // swizzled source chunk offset (u16)
  const u16* qbp = qoc + ((size_t)bhl * N_ + q0) * HD;
  const u16* kb = koc + (size_t)bhl * N_ * HD;
  const u16* vb = vTc + (size_t)bhl * HD * N_;

#define STAGE_KV(OFF, key0)                                                   \
  do {                                                                        \
    g2l16(kb + (size_t)((key0) + sr) * HD + swo,      Ks + (OFF) + t * 8);    \
    g2l16(kb + (size_t)((key0) + 32 + sr) * HD + swo, Ks + (OFF) + 2048 + t * 8); \
    g2l16(vb + (size_t)sr * N_ + (key0) + swo,        Vs + (OFF) + t * 8);    \
    g2l16(vb + (size_t)(32 + sr) * N_ + (key0) + swo, Vs + (OFF) + 2048 + t * 8); \
  } while (0)

  g2l16(qbp + (size_t)(sr) * HD + swo,       Qs + t * 8);
  g2l16(qbp + (size_t)(32 + sr) * HD + swo,  Qs + 2048 + t * 8);
  g2l16(qbp + (size_t)(64 + sr) * HD + swo,  Qs + 4096 + t * 8);
  g2l16(qbp + (size_t)(96 + sr) * HD + swo,  Qs + 6144 + t * 8);
  STAGE_KV(0, 0);
  STAGE_KV(4096, 64);
  SW4();   // Q(4) + KV0(4) done; KV1's 4 in flight
  BARF();

  int sA = (quad ^ (l15 & 7)) * 8;  // swizzled slot, contraction chunks 0-3
  int sB = sA ^ 32;                 // chunks 4-7
  bf16x8 aq00 = *(const bf16x8*)&Qs[(w * 16 + l15) * 64 + sA];
  bf16x8 aq01 = *(const bf16x8*)&Qs[(w * 16 + l15) * 64 + sB];
  bf16x8 aq10 = *(const bf16x8*)&Qs[(64 + w * 16 + l15) * 64 + sA];
  bf16x8 aq11 = *(const bf16x8*)&Qs[(64 + w * 16 + l15) * 64 + sB];
  f4 o0[4], o1[4];
  for (int i = 0; i < 4; ++i) {
    o0[i] = (f4){0.f, 0.f, 0.f, 0.f};
    o1[i] = (f4){0.f, 0.f, 0.f, 0.f};
  }
  f4 ls0 = (f4){0.f, 0.f, 0.f, 0.f};
  f4 ls1 = (f4){0.f, 0.f, 0.f, 0.f};
  bf16x8 ones;
  for (int i = 0; i < 8; ++i) ones[i] = (short)0x3F80;  // bf16 1.0

#define TILE_STEP(KOFF)                                                       \
  do {                                                                        \
    f4 s0_[4], s1_[4];                                                        \
    __builtin_amdgcn_s_setprio(1);                                            \
    _Pragma("unroll")                                                         \
    for (int ni = 0; ni < 4; ++ni) {                                          \
      bf16x8 b0v = *(const bf16x8*)&Ks[(KOFF) + (ni * 16 + l15) * 64 + sA];   \
      bf16x8 b1v = *(const bf16x8*)&Ks[(KOFF) + (ni * 16 + l15) * 64 + sB];   \
      f4 z0 = (f4){0.f, 0.f, 0.f, 0.f};                                       \
      z0 = __builtin_amdgcn_mfma_f32_16x16x32_bf16(aq00, b0v, z0, 0, 0, 0);   \
      z0 = __builtin_amdgcn_mfma_f32_16x16x32_bf16(aq01, b1v, z0, 0, 0, 0);   \
      s0_[ni] = z0;                                                           \
      f4 z1 = (f4){0.f, 0.f, 0.f, 0.f};                                       \
      z1 = __builtin_amdgcn_mfma_f32_16x16x32_bf16(aq10, b0v, z1, 0, 0, 0);   \
      z1 = __builtin_amdgcn_mfma_f32_16x16x32_bf16(aq11, b1v, z1, 0, 0, 0);   \
      s1_[ni] = z1;                                                           \
    }                                                                         \
    __builtin_amdgcn_s_setprio(0);                                            \
    _Pragma("unroll")                                                         \
    for (int ni = 0; ni < 4; ++ni)                                            \
      _Pragma("unroll")                                                       \
      for (int r = 0; r < 4; ++r) {                                           \
        Ps[(w * 16 + quad * 4 + r) * 72 + ni * 16 + l15] =                    \
            f2bf(__expf(s0_[ni][r] * 0.125f));                                \
        Ps[(64 + w * 16 + quad * 4 + r) * 72 + ni * 16 + l15] =               \
            f2bf(__expf(s1_[ni][r] * 0.125f));                                \
      }                                                                       \
    bf16x8 ap00 = *(const bf16x8*)&Ps[(w * 16 + l15) * 72 + quad * 8];        \
    bf16x8 ap01 = *(const bf16x8*)&Ps[(w * 16 + l15) * 72 + 32 + quad * 8];   \
    bf16x8 ap10 = *(const bf16x8*)&Ps[(64 + w * 16 + l15) * 72 + quad * 8];   \
    bf16x8 ap11 = *(const bf16x8*)&Ps[(64 + w * 16 + l15) * 72 + 32 + quad * 8]; \
    __builtin_amdgcn_s_setprio(1);                                            \
    _Pragma("unroll")                                                         \
    for (int ni = 0; ni < 4; ++ni) {                                          \
      bf16x8 b0v = *(const bf16x8*)&Vs[(KOFF) + (ni * 16 + l15) * 64 + sA];   \
      bf16x8 b1v = *(const bf16x8*)&Vs[(KOFF) + (ni * 16 + l15) * 64 + sB];   \
      o0[ni] = __builtin_amdgcn_mfma_f32_16x16x32_bf16(ap00, b0v, o0[ni], 0, 0, 0); \
      o0[ni] = __builtin_amdgcn_mfma_f32_16x16x32_bf16(ap01, b1v, o0[ni], 0, 0, 0); \
      o1[ni] = __builtin_amdgcn_mfma_f32_16x16x32_bf16(ap10, b0v, o1[ni], 0, 0, 0); \
      o1[ni] = __builtin_amdgcn_mfma_f32_16x16x32_bf16(ap11, b1v, o1[ni], 0, 0, 0); \
    }                                                                         \
    ls0 = __builtin_amdgcn_mfma_f32_16x16x32_bf16(ap00, ones, ls0, 0, 0, 0);  \
    ls0 = __builtin_amdgcn_mfma_f32_16x16x32_bf16(ap01, ones, ls0, 0, 0, 0);  \
    ls1 = __builtin_amdgcn_mfma_f32_16x16x32_bf16(ap10, ones, ls1, 0, 0, 0);  \
    ls1 = __builtin_amdgcn_mfma_f32_16x16x32_bf16(ap11, ones, ls1, 0, 0, 0);  \
    __builtin_amdgcn_s_setprio(0);                                            \
  } while (0)

  for (int kt = 0; kt < 16; kt += 2) {
    TILE_STEP(0);
    BARF();                                   // done reading KV half 0
    if (kt + 2 < 16) { STAGE_KV(0, (kt + 2) * 64); SW4(); } else { SW0(); }
    BARF();                                   // KV half 1 visible
    TILE_STEP(4096);
    BARF();                                   // done reading KV half 1
    if (kt + 3 < 16) { STAGE_KV(4096, (kt + 3) * 64); SW4(); } else { SW0(); }
    BARF();                                   // KV half 0 visible
  }
#undef TILE_STEP
#undef STAGE_KV

  for (int ni = 0; ni < 4; ++ni)
    for (int r = 0; r < 4; ++r) {
      Ps[(w * 16 + quad * 4 + r) * 72 + ni * 16 + l15] =
          f2bf(o0[ni][r] / ls0[r]);
      Ps[(64 + w * 16 + quad * 4 + r) * 72 + ni * 16 + l15] =
          f2bf(o1[ni][r] / ls1[r]);
    }
  __syncthreads();
  {
    int rr = t >> 1, cc = t & 1;                 // 128 rows x 2 chunks of 32
    int n = q0 + rr;
    const u16* src = Ps + rr * 72 + cc * 32;
    u16* dst = aoc + ((size_t)bl * N_ + n) * C_ + h * HD + cc * 32;
    for (int c = 0; c < 4; ++c)
      *(bf16x8*)(dst + c * 8) = *(const bf16x8*)(src + c * 8);
  }
}

// ---------------- K4: output projection GEMM (R3-exact) ------------------
// 128x64 tiles, depth-2 counted-vmcnt pipeline.
__global__ __launch_bounds__(256, 2) void gemm_proj(const u16* __restrict__ aoc,
                                                    const u16* __restrict__ pwb,
                                                    const float* __restrict__ bias,
                                                    float* __restrict__ out,
                                                    int b0) {
  __shared__ u16 smem[12288];  // 2 bufs x (A 4096 + B 2048)
  int t = threadIdx.x, l = t & 63;
  int quad = l >> 4, l15 = l & 15;
  int w = t >> 6, wm = w & 1, wn = w >> 1;
  int m0l = blockIdx.x * 128, n0 = blockIdx.y * 64;
  f4 acc[4][2];
  for (int i = 0; i < 4; ++i)
    for (int j = 0; j < 2; ++j) acc[i][j] = (f4){0.f, 0.f, 0.f, 0.f};
  int row = t >> 2, colb = (t & 3) * 8;
  const u16* ga = aoc + (size_t)(m0l + row) * C_ + colb;
  const u16* gw = pwb + (size_t)(n0 + row) * C_ + colb;

#define STAGE_P(OFF, kk)                                   \
  do {                                                     \
    u16* p_ = smem + (OFF);                                \
    g2l16(ga + (kk),           p_ + t * 8);                \
    g2l16(ga + (kk) + 64 * C_, p_ + 2048 + t * 8);         \
    g2l16(gw + (kk),           p_ + 4096 + t * 8);         \
  } while (0)

#define COMPUTE_P(OFF)                                                        \
  do {                                                                        \
    const u16* base = smem + (OFF);                                           \
    bf16x8 af[4], bfr[2];                                                     \
    for (int i = 0; i < 4; ++i)                                               \
      af[i] = *(const bf16x8*)&base[(wm * 64 + i * 16 + l15) * 32 + quad * 8];\
    for (int j = 0; j < 2; ++j)                                               \
      bfr[j] = *(const bf16x8*)&base[4096 + (wn * 32 + j * 16 + l15) * 32 + quad * 8]; \
    for (int i = 0; i < 4; ++i)                                               \
      for (int j = 0; j < 2; ++j)                                             \
        acc[i][j] = __builtin_amdgcn_mfma_f32_16x16x32_bf16(af[i], bfr[j], acc[i][j], 0, 0, 0); \
  } while (0)

  STAGE_P(0, 0);
  STAGE_P(6144, 32);
  SW3();
  BARF();
  for (int n = 0; n < 24; n += 2) {
    COMPUTE_P(0);
    BARF();
    if (n + 2 < 24) { STAGE_P(0, (n + 2) * 32); SW3(); } else { SW0(); }
    BARF();
    COMPUTE_P(6144);
    BARF();
    if (n + 3 < 24) { STAGE_P(6144, (n + 3) * 32); SW3(); } else { SW0(); }
    BARF();
  }
#undef STAGE_P
#undef COMPUTE_P

  for (int j = 0; j < 2; ++j) {
    int gcol = n0 + wn * 32 + j * 16 + l15;
    float bv = bias[gcol];
    for (int i = 0; i < 4; ++i) {
      int rbase = m0l + wm * 64 + i * 16 + quad * 4;
      for (int r = 0; r < 4; ++r)
        __builtin_nontemporal_store(acc[i][j][r] + bv,
                                    &out[(size_t)(b0 * N_ + rbase + r) * C_ + gcol]);
    }
  }
}

extern "C" void kernel_launch(void* const* d_in, const int* in_sizes, int n_in,
                              void* d_out, int out_size, void* d_ws, size_t ws_size,
                              hipStream_t stream) {
  const float* x   = (const float*)d_in[0];
  const float* y   = (const float*)d_in[1];
  const float* qw  = (const float*)d_in[2];
  const float* qb  = (const float*)d_in[3];
  const float* kvw = (const float*)d_in[4];
  const float* kvb = (const float*)d_in[5];
  const float* pw  = (const float*)d_in[6];
  const float* pb  = (const float*)d_in[7];
  const float* lg  = (const float*)d_in[8];
  const float* lb  = (const float*)d_in[9];

  char* ws = (char*)d_ws;
  float* mu = (float*)(ws);
  float* rs = (float*)(ws + 32768);
  u16* qwb  = (u16*)(ws + 65536);
  u16* kvwb = (u16*)(ws + 1245184);
  u16* pwb  = (u16*)(ws + 3604480);
  const size_t BASE2 = 4784128;
  const size_t PER_B = 1572864;

  int nb = 1;
  for (int c = 8; c >= 1; c >>= 1) {
    if (BASE2 + 5 * (size_t)c * PER_B <= ws_size) { nb = c; break; }
  }
  u16* xbc = (u16*)(ws + BASE2);
  u16* y2c = (u16*)(ws + BASE2 + (size_t)nb * PER_B);
  u16* qoc = (u16*)(ws + BASE2 + 2 * (size_t)nb * PER_B);
  u16* koc = (u16*)(ws + BASE2 + 3 * (size_t)nb * PER_B);
  u16* vTc = (u16*)(ws + BASE2 + 4 * (size_t)nb * PER_B);
  u16* aoc = xbc;

  cvt_bf16<<<dim3(576), dim3(256), 0, stream>>>(qw, qwb, 147456);
  cvt_bf16<<<dim3(1152), dim3(256), 0, stream>>>(kvw, kvwb, 294912);
  cvt_bf16<<<dim3(576), dim3(256), 0, stream>>>(pw, pwb, 147456);

  for (int b0 = 0; b0 < B_; b0 += nb) {
    cvt_bf16<<<dim3(768 * nb), dim3(256), 0, stream>>>(
        x + (size_t)b0 * N_ * C_, xbc, nb * 196608);
    ln_stats<<<dim3(16 * nb), dim3(256), 0, stream>>>(y, mu, rs, b0);
    ln_apply<<<dim3(16, 12, nb), dim3(256), 0, stream>>>(y, mu, rs, lg, lb, y2c, b0);
    gemm_gate<<<dim3(8 * nb, 18), dim3(256), 0, stream>>>(xbc, y2c, qwb, kvwb,
                                                          qb, kvb, qoc, koc, vTc);
    attn<<<dim3(8, 12 * nb), dim3(256), 0, stream>>>(qoc, koc, vTc, aoc);
    gemm_proj<<<dim3(8 * nb, 12), dim3(256), 0, stream>>>(aoc, pwb, pb, (float*)d_out, b0);
  }
}

// Round 9
// 276.113 us; speedup vs baseline: 1.0906x; 1.0313x over previous
//
#include <hip/hip_runtime.h>
#include <stdint.h>

typedef __attribute__((ext_vector_type(4))) float f4;
typedef __attribute__((ext_vector_type(8))) short bf16x8;
typedef __attribute__((ext_vector_type(4))) unsigned short u16x4;
typedef unsigned short u16;

#define B_ 8
#define N_ 1024
#define C_ 768
#define NH 12
#define HD 64

__device__ __forceinline__ float bf2f(u16 v) {
  union { unsigned u; float f; } x; x.u = ((unsigned)v) << 16; return x.f;
}
__device__ __forceinline__ u16 f2bf(float f) {
  union { float f; unsigned u; } x; x.f = f;
  unsigned r = x.u + 0x7FFFu + ((x.u >> 16) & 1u);
  return (u16)(r >> 16);
}
// async global->LDS, 16B per lane
__device__ __forceinline__ void g2l16(const u16* g, const u16* l) {
  __builtin_amdgcn_global_load_lds(
      (const __attribute__((address_space(1))) void*)(uintptr_t)g,
      (__attribute__((address_space(3))) void*)(uint32_t)(uintptr_t)l,
      16, 0, 0);
}

// counted vmem waits (T4): never drain to 0 in the main loop
#define SW12() asm volatile("s_waitcnt vmcnt(12)" ::: "memory")
#define SW6()  asm volatile("s_waitcnt vmcnt(6)" ::: "memory")
#define SW4()  asm volatile("s_waitcnt vmcnt(4)" ::: "memory")
#define SW3()  asm volatile("s_waitcnt vmcnt(3)" ::: "memory")
#define SW0()  asm volatile("s_waitcnt vmcnt(0)" ::: "memory")
// raw barrier + compile/IR fence (rule #18)
#define BARF()                              \
  do {                                      \
    __builtin_amdgcn_s_barrier();           \
    asm volatile("" ::: "memory");          \
    __builtin_amdgcn_sched_barrier(0);      \
  } while (0)

// ---------------- cvt: fp32 -> bf16, vectorized x4 ----------------
__global__ __launch_bounds__(256) void cvt_bf16(const float* __restrict__ s,
                                                u16* __restrict__ d, int n4) {
  int i = blockIdx.x * 256 + threadIdx.x;
  int stride = gridDim.x * 256;
  for (; i < n4; i += stride) {
    float4 v = ((const float4*)s)[i];
    u16x4 o;
    o.x = f2bf(v.x); o.y = f2bf(v.y); o.z = f2bf(v.z); o.w = f2bf(v.w);
    ((u16x4*)d)[i] = o;
  }
}

// ---------------- K0+K1 fused: LN stats + transpose + normalize ----------
// One pass over y: block = 32 n-rows x full C. Streams y once (stats in
// fp32), caches bf16 in LDS, then normalizes from LDS and writes y2c.
// 256 blocks x 512 threads (full GPU); replaces ln_stats (128-block,
// half-idle) + ln_apply (second 100MB read of y).
__global__ __launch_bounds__(512) void ln_fused(const float* __restrict__ y,
                                                const float* __restrict__ lg,
                                                const float* __restrict__ lb,
                                                u16* __restrict__ y2c,
                                                int b0) {
  __shared__ u16 ybuf[768 * 33];          // [c][n 0..31], pitch 33 u16
  __shared__ float ps[16][32], pq[16][32];
  __shared__ float smu[32], srs[32];
  int t = threadIdx.x;
  int nl = t & 31, ch = t >> 5;           // 16 c-groups of 48
  int idx0 = b0 * N_ + blockIdx.x * 32;   // flat n-index
  int b = idx0 >> 10, nb_ = idx0 & 1023;
  const float* p = y + (size_t)b * C_ * N_ + nb_ + nl;
  float s = 0.f, q = 0.f;
  int c0 = ch * 48;
  for (int c = c0; c < c0 + 48; ++c) {
    float v = p[(size_t)c * N_];
    s += v; q += v * v;
    ybuf[c * 33 + nl] = f2bf(v);
  }
  ps[ch][nl] = s; pq[ch][nl] = q;
  __syncthreads();
  if (t < 32) {
    float ts = 0.f, tq = 0.f;
    for (int g = 0; g < 16; ++g) { ts += ps[g][t]; tq += pq[g][t]; }
    float m = ts * (1.f / C_);
    float var = tq * (1.f / C_) - m * m;
    smu[t] = m;
    srs[t] = rsqrtf(fmaxf(var, 0.f) + 1e-5f);
  }
  __syncthreads();
  // write phase: thread (rn = t>>4, cg = t&15) writes 48 c's of row rn
  int rn = t >> 4, cg = t & 15;
  float m = smu[rn], rr = srs[rn];
  int bl = b - b0;
  int n = nb_ + rn;
  u16* dst = y2c + ((size_t)bl * N_ + n) * C_ + cg * 48;
  for (int cc = 0; cc < 48; cc += 8) {
    int c = cg * 48 + cc;
    bf16x8 o;
    for (int j = 0; j < 8; ++j) {
      float v = bf2f(ybuf[(c + j) * 33 + rn]);
      o[j] = (short)f2bf((v - m) * rr * lg[c + j] + lb[c + j]);
    }
    *(bf16x8*)(dst + cc) = o;
  }
}

// ---------------- K2: merged dual-A gated GEMM (R5-exact, best: 90us) ----
// Depth-3 pipeline, counted vmcnt(12), XOR-swizzled LDS, 128x128 tiles.
__global__ __launch_bounds__(256, 2) void gemm_gate(
    const u16* __restrict__ xbc, const u16* __restrict__ y2c,
    const u16* __restrict__ qwb, const u16* __restrict__ kvwb,
    const float* __restrict__ qb_, const float* __restrict__ kvb_,
    u16* __restrict__ o_q, u16* __restrict__ o_k, u16* __restrict__ o_vT) {
  __shared__ u16 smem[36864];  // 3 bufs x 12288 u16 (72 KiB); epilogue reuses front
  int t = threadIdx.x, l = t & 63;
  int quad = l >> 4, l15 = l & 15;
  int w = t >> 6, wm = w & 1, wn = w >> 1;
  int m0l = blockIdx.x * 128;
  int n0l = blockIdx.y * 128;

  const u16* wp; const float* bp; int sel, h0;
  if (n0l < C_) {
    wp = qwb + (size_t)n0l * C_; bp = qb_ + n0l; sel = 0; h0 = n0l >> 6;
  } else {
    int nk = n0l - C_;
    wp = kvwb + (size_t)nk * C_; bp = kvb_ + nk;
    sel = (nk < C_) ? 1 : 2;
    h0 = ((sel == 2) ? nk - C_ : nk) >> 6;
  }

  f4 accx[4][4], accy[4][4];
  for (int i = 0; i < 4; ++i)
    for (int j = 0; j < 4; ++j) {
      accx[i][j] = (f4){0.f, 0.f, 0.f, 0.f};
      accy[i][j] = (f4){0.f, 0.f, 0.f, 0.f};
    }

  int row = t >> 2;
  int colS = (((t & 3) ^ (row & 3)) * 8);   // pre-swizzled source chunk
  const u16* gx = xbc + (size_t)(m0l + row) * C_ + colS;
  const u16* gy = y2c + (size_t)(m0l + row) * C_ + colS;
  const u16* gw = wp + (size_t)row * C_ + colS;
  int rsl = (quad ^ (l15 & 3)) * 8;         // swizzled read slot (u16)

#define STAGE_G(OFF, kk)                                   \
  do {                                                     \
    u16* p_ = smem + (OFF);                                \
    g2l16(gx + (kk),           p_ + t * 8);                \
    g2l16(gx + (kk) + 64 * C_, p_ + 2048 + t * 8);         \
    g2l16(gy + (kk),           p_ + 4096 + t * 8);         \
    g2l16(gy + (kk) + 64 * C_, p_ + 6144 + t * 8);         \
    g2l16(gw + (kk),           p_ + 8192 + t * 8);         \
    g2l16(gw + (kk) + 64 * C_, p_ + 10240 + t * 8);        \
  } while (0)

#define COMPUTE_G(OFF)                                                        \
  do {                                                                        \
    const u16* base = smem + (OFF);                                           \
    bf16x8 afx[4], afy[4], bfr[4];                                            \
    for (int i = 0; i < 4; ++i) {                                             \
      int ra = (wm * 64 + i * 16 + l15) * 32 + rsl;                           \
      afx[i] = *(const bf16x8*)&base[ra];                                     \
      afy[i] = *(const bf16x8*)&base[4096 + ra];                              \
      int rb = (wn * 64 + i * 16 + l15) * 32 + rsl;                           \
      bfr[i] = *(const bf16x8*)&base[8192 + rb];                              \
    }                                                                         \
    for (int i = 0; i < 4; ++i)                                               \
      for (int j = 0; j < 4; ++j) {                                           \
        accx[i][j] = __builtin_amdgcn_mfma_f32_16x16x32_bf16(afx[i], bfr[j], accx[i][j], 0, 0, 0); \
        accy[i][j] = __builtin_amdgcn_mfma_f32_16x16x32_bf16(afy[i], bfr[j], accy[i][j], 0, 0, 0); \
      }                                                                       \
  } while (0)

#define STEP_G(i, OFF)                                        \
  do {                                                        \
    COMPUTE_G(OFF);                                           \
    BARF();                                                   \
    if ((i) < 21)      { STAGE_G(OFF, ((i) + 3) * 32); SW12(); } \
    else if ((i) == 21) SW6();                                \
    else if ((i) == 22) SW0();                                \
    BARF();                                                   \
  } while (0)

  STAGE_G(0, 0);
  STAGE_G(12288, 32);
  STAGE_G(24576, 64);
  SW12();   // tile0 done (tiles 1,2 in flight)
  BARF();
#pragma unroll
  for (int n = 0; n < 24; n += 3) {
    STEP_G(n, 0);
    STEP_G(n + 1, 12288);
    STEP_G(n + 2, 24576);
  }
#undef STEP_G
#undef STAGE_G
#undef COMPUTE_G

  // epilogue: gate -> LDS tile -> cached 16-B stores
  const int PITCH = 136;
  for (int j = 0; j < 4; ++j) {
    int cloc = wn * 64 + j * 16 + l15;
    float bias = bp[cloc];
    for (int i = 0; i < 4; ++i) {
      int rb0 = wm * 64 + i * 16 + quad * 4;
      for (int r = 0; r < 4; ++r) {
        int rloc = rb0 + r;
        float vx = accx[i][j][r] + bias;
        float vy = accy[i][j][r] + bias;
        float gg = 1.f / (1.f + __expf(-vy));
        float val = (sel == 0) ? vx * (1.f + gg) : gg * (vx + 1.f);
        u16 bv = f2bf(val);
        if (sel == 2) smem[cloc * PITCH + rloc] = bv;   // v staged transposed
        else          smem[rloc * PITCH + cloc] = bv;
      }
    }
  }
  __syncthreads();
  {
    int rr = t >> 1, hh = t & 1;
    const u16* src = smem + rr * PITCH + hh * 64;
    u16* dst;
    if (sel == 2) {
      int h = h0 + (rr >> 6), d = rr & 63;
      int bl = m0l >> 10, nbase = m0l & 1023;
      dst = o_vT + (size_t)((bl * NH + h) * HD + d) * N_ + nbase + hh * 64;
    } else {
      int gml = m0l + rr;
      int bl = gml >> 10, n = gml & 1023;
      int h = h0 + hh;
      dst = (sel == 0 ? o_q : o_k) + (size_t)((bl * NH + h) * N_ + n) * HD;
    }
    for (int c = 0; c < 8; ++c) {
      bf16x8 v = *(const bf16x8*)(src + c * 8);
      *(bf16x8*)(dst + c * 8) = v;
    }
  }
}

// ---------------- K3: fused attention (R3-exact, best known) -------------
__global__ __launch_bounds__(256) void attn(const u16* __restrict__ qoc,
                                            const u16* __restrict__ koc,
                                            const u16* __restrict__ vTc,
                                            u16* __restrict__ aoc) {
  __shared__ u16 Qs[4096], Ks[8192], Vs[8192];
  __shared__ u16 Ps[64 * 72];
  int t = threadIdx.x, l = t & 63, w = t >> 6;
  int quad = l >> 4, l15 = l & 15;
  int bhl = blockIdx.y;
  int bl = bhl / NH, h = bhl % NH;
  int q0 = blockIdx.x * 64;
  int sr = t >> 3;                       // staging row (0..31, +32 second half)
  int swo = ((t & 7) ^ (sr & 7)) * 8;    // swizzled source chunk offset (u16)
  const u16* qbp = qoc + ((size_t)bhl * N_ + q0) * HD;
  const u16* kb = koc + (size_t)bhl * N_ * HD;
  const u16* vb = vTc + (size_t)bhl * HD * N_;

#define STAGE_KV(OFF, key0)                                                   \
  do {                                                                        \
    g2l16(kb + (size_t)((key0) + sr) * HD + swo,      Ks + (OFF) + t * 8);    \
    g2l16(kb + (size_t)((key0) + 32 + sr) * HD + swo, Ks + (OFF) + 2048 + t * 8); \
    g2l16(vb + (size_t)sr * N_ + (key0) + swo,        Vs + (OFF) + t * 8);    \
    g2l16(vb + (size_t)(32 + sr) * N_ + (key0) + swo, Vs + (OFF) + 2048 + t * 8); \
  } while (0)

  g2l16(qbp + sr * HD + swo,        Qs + t * 8);
  g2l16(qbp + (32 + sr) * HD + swo, Qs + 2048 + t * 8);
  STAGE_KV(0, 0);
  STAGE_KV(4096, 64);
  SW4();   // Q(2) + KV0(4) done; KV1's 4 in flight
  BARF();

  int sA = (quad ^ (l15 & 7)) * 8;  // swizzled slot, contraction chunks 0-3
  int sB = sA ^ 32;                 // chunks 4-7
  bf16x8 aq0 = *(const bf16x8*)&Qs[(w * 16 + l15) * 64 + sA];
  bf16x8 aq1 = *(const bf16x8*)&Qs[(w * 16 + l15) * 64 + sB];
  f4 o[4];
  for (int i = 0; i < 4; ++i) o[i] = (f4){0.f, 0.f, 0.f, 0.f};
  f4 ls = (f4){0.f, 0.f, 0.f, 0.f};
  bf16x8 ones;
  for (int i = 0; i < 8; ++i) ones[i] = (short)0x3F80;  // bf16 1.0

#define TILE_STEP(KOFF)                                                       \
  do {                                                                        \
    f4 s_[4];                                                                 \
    __builtin_amdgcn_s_setprio(1);                                            \
    for (int ni = 0; ni < 4; ++ni) {                                          \
      bf16x8 b0v = *(const bf16x8*)&Ks[(KOFF) + (ni * 16 + l15) * 64 + sA];   \
      bf16x8 b1v = *(const bf16x8*)&Ks[(KOFF) + (ni * 16 + l15) * 64 + sB];   \
      f4 z = (f4){0.f, 0.f, 0.f, 0.f};                                        \
      z = __builtin_amdgcn_mfma_f32_16x16x32_bf16(aq0, b0v, z, 0, 0, 0);      \
      z = __builtin_amdgcn_mfma_f32_16x16x32_bf16(aq1, b1v, z, 0, 0, 0);      \
      s_[ni] = z;                                                             \
    }                                                                         \
    __builtin_amdgcn_s_setprio(0);                                            \
    for (int ni = 0; ni < 4; ++ni)                                            \
      for (int r = 0; r < 4; ++r)                                             \
        Ps[(w * 16 + quad * 4 + r) * 72 + ni * 16 + l15] =                    \
            f2bf(__expf(s_[ni][r] * 0.125f));                                 \
    bf16x8 ap0 = *(const bf16x8*)&Ps[(w * 16 + l15) * 72 + quad * 8];         \
    bf16x8 ap1 = *(const bf16x8*)&Ps[(w * 16 + l15) * 72 + 32 + quad * 8];    \
    __builtin_amdgcn_s_setprio(1);                                            \
    for (int ni = 0; ni < 4; ++ni) {                                          \
      bf16x8 b0v = *(const bf16x8*)&Vs[(KOFF) + (ni * 16 + l15) * 64 + sA];   \
      bf16x8 b1v = *(const bf16x8*)&Vs[(KOFF) + (ni * 16 + l15) * 64 + sB];   \
      o[ni] = __builtin_amdgcn_mfma_f32_16x16x32_bf16(ap0, b0v, o[ni], 0, 0, 0); \
      o[ni] = __builtin_amdgcn_mfma_f32_16x16x32_bf16(ap1, b1v, o[ni], 0, 0, 0); \
    }                                                                         \
    ls = __builtin_amdgcn_mfma_f32_16x16x32_bf16(ap0, ones, ls, 0, 0, 0);     \
    ls = __builtin_amdgcn_mfma_f32_16x16x32_bf16(ap1, ones, ls, 0, 0, 0);     \
    __builtin_amdgcn_s_setprio(0);                                            \
  } while (0)

  for (int kt = 0; kt < 16; kt += 2) {
    TILE_STEP(0);
    BARF();                                   // done reading KV half 0
    if (kt + 2 < 16) { STAGE_KV(0, (kt + 2) * 64); SW4(); } else { SW0(); }
    BARF();                                   // KV half 1 visible
    TILE_STEP(4096);
    BARF();                                   // done reading KV half 1
    if (kt + 3 < 16) { STAGE_KV(4096, (kt + 3) * 64); SW4(); } else { SW0(); }
    BARF();                                   // KV half 0 visible
  }
#undef TILE_STEP
#undef STAGE_KV

  for (int ni = 0; ni < 4; ++ni)
    for (int r = 0; r < 4; ++r)
      Ps[(w * 16 + quad * 4 + r) * 72 + ni * 16 + l15] =
          f2bf(o[ni][r] / ls[r]);
  __syncthreads();
  {
    int rr = t >> 2, cc = t & 3;
    int n = q0 + rr;
    const u16* src = Ps + rr * 72 + cc * 16;
    u16* dst = aoc + ((size_t)bl * N_ + n) * C_ + h * HD + cc * 16;
    *(bf16x8*)dst = *(const bf16x8*)src;
    *(bf16x8*)(dst + 8) = *(const bf16x8*)(src + 8);
  }
}

// ---------------- K4: output projection GEMM (R3-exact, best known) ------
// 128x64 tiles, depth-2 counted-vmcnt pipeline.
__global__ __launch_bounds__(256, 2) void gemm_proj(const u16* __restrict__ aoc,
                                                    const u16* __restrict__ pwb,
                                                    const float* __restrict__ bias,
                                                    float* __restrict__ out,
                                                    int b0) {
  __shared__ u16 smem[12288];  // 2 bufs x (A 4096 + B 2048)
  int t = threadIdx.x, l = t & 63;
  int quad = l >> 4, l15 = l & 15;
  int w = t >> 6, wm = w & 1, wn = w >> 1;
  int m0l = blockIdx.x * 128, n0 = blockIdx.y * 64;
  f4 acc[4][2];
  for (int i = 0; i < 4; ++i)
    for (int j = 0; j < 2; ++j) acc[i][j] = (f4){0.f, 0.f, 0.f, 0.f};
  int row = t >> 2, colb = (t & 3) * 8;
  const u16* ga = aoc + (size_t)(m0l + row) * C_ + colb;
  const u16* gw = pwb + (size_t)(n0 + row) * C_ + colb;

#define STAGE_P(OFF, kk)                                   \
  do {                                                     \
    u16* p_ = smem + (OFF);                                \
    g2l16(ga + (kk),           p_ + t * 8);                \
    g2l16(ga + (kk) + 64 * C_, p_ + 2048 + t * 8);         \
    g2l16(gw + (kk),           p_ + 4096 + t * 8);         \
  } while (0)

#define COMPUTE_P(OFF)                                                        \
  do {                                                                        \
    const u16* base = smem + (OFF);                                           \
    bf16x8 af[4], bfr[2];                                                     \
    for (int i = 0; i < 4; ++i)                                               \
      af[i] = *(const bf16x8*)&base[(wm * 64 + i * 16 + l15) * 32 + quad * 8];\
    for (int j = 0; j < 2; ++j)                                               \
      bfr[j] = *(const bf16x8*)&base[4096 + (wn * 32 + j * 16 + l15) * 32 + quad * 8]; \
    for (int i = 0; i < 4; ++i)                                               \
      for (int j = 0; j < 2; ++j)                                             \
        acc[i][j] = __builtin_amdgcn_mfma_f32_16x16x32_bf16(af[i], bfr[j], acc[i][j], 0, 0, 0); \
  } while (0)

  STAGE_P(0, 0);
  STAGE_P(6144, 32);
  SW3();
  BARF();
  for (int n = 0; n < 24; n += 2) {
    COMPUTE_P(0);
    BARF();
    if (n + 2 < 24) { STAGE_P(0, (n + 2) * 32); SW3(); } else { SW0(); }
    BARF();
    COMPUTE_P(6144);
    BARF();
    if (n + 3 < 24) { STAGE_P(6144, (n + 3) * 32); SW3(); } else { SW0(); }
    BARF();
  }
#undef STAGE_P
#undef COMPUTE_P

  for (int j = 0; j < 2; ++j) {
    int gcol = n0 + wn * 32 + j * 16 + l15;
    float bv = bias[gcol];
    for (int i = 0; i < 4; ++i) {
      int rbase = m0l + wm * 64 + i * 16 + quad * 4;
      for (int r = 0; r < 4; ++r)
        __builtin_nontemporal_store(acc[i][j][r] + bv,
                                    &out[(size_t)(b0 * N_ + rbase + r) * C_ + gcol]);
    }
  }
}

extern "C" void kernel_launch(void* const* d_in, const int* in_sizes, int n_in,
                              void* d_out, int out_size, void* d_ws, size_t ws_size,
                              hipStream_t stream) {
  const float* x   = (const float*)d_in[0];
  const float* y   = (const float*)d_in[1];
  const float* qw  = (const float*)d_in[2];
  const float* qb  = (const float*)d_in[3];
  const float* kvw = (const float*)d_in[4];
  const float* kvb = (const float*)d_in[5];
  const float* pw  = (const float*)d_in[6];
  const float* pb  = (const float*)d_in[7];
  const float* lg  = (const float*)d_in[8];
  const float* lb  = (const float*)d_in[9];

  char* ws = (char*)d_ws;
  u16* qwb  = (u16*)(ws + 65536);
  u16* kvwb = (u16*)(ws + 1245184);
  u16* pwb  = (u16*)(ws + 3604480);
  const size_t BASE2 = 4784128;
  const size_t PER_B = 1572864;

  int nb = 1;
  for (int c = 8; c >= 1; c >>= 1) {
    if (BASE2 + 5 * (size_t)c * PER_B <= ws_size) { nb = c; break; }
  }
  u16* xbc = (u16*)(ws + BASE2);
  u16* y2c = (u16*)(ws + BASE2 + (size_t)nb * PER_B);
  u16* qoc = (u16*)(ws + BASE2 + 2 * (size_t)nb * PER_B);
  u16* koc = (u16*)(ws + BASE2 + 3 * (size_t)nb * PER_B);
  u16* vTc = (u16*)(ws + BASE2 + 4 * (size_t)nb * PER_B);
  u16* aoc = xbc;

  cvt_bf16<<<dim3(576), dim3(256), 0, stream>>>(qw, qwb, 147456);
  cvt_bf16<<<dim3(1152), dim3(256), 0, stream>>>(kvw, kvwb, 294912);
  cvt_bf16<<<dim3(576), dim3(256), 0, stream>>>(pw, pwb, 147456);

  for (int b0 = 0; b0 < B_; b0 += nb) {
    cvt_bf16<<<dim3(768 * nb), dim3(256), 0, stream>>>(
        x + (size_t)b0 * N_ * C_, xbc, nb * 196608);
    ln_fused<<<dim3(32 * nb), dim3(512), 0, stream>>>(y, lg, lb, y2c, b0);
    gemm_gate<<<dim3(8 * nb, 18), dim3(256), 0, stream>>>(xbc, y2c, qwb, kvwb,
                                                          qb, kvb, qoc, koc, vTc);
    attn<<<dim3(16, 12 * nb), dim3(256), 0, stream>>>(qoc, koc, vTc, aoc);
    gemm_proj<<<dim3(8 * nb, 12), dim3(256), 0, stream>>>(aoc, pwb, pb, (float*)d_out, b0);
  }
}

// Round 10
// 270.425 us; speedup vs baseline: 1.1136x; 1.0210x over previous
//
#include <hip/hip_runtime.h>
#include <stdint.h>

typedef __attribute__((ext_vector_type(4))) float f4;
typedef __attribute__((ext_vector_type(8))) short bf16x8;
typedef __attribute__((ext_vector_type(4))) unsigned short u16x4;
typedef unsigned short u16;

#define B_ 8
#define N_ 1024
#define C_ 768
#define NH 12
#define HD 64

__device__ __forceinline__ float bf2f(u16 v) {
  union { unsigned u; float f; } x; x.u = ((unsigned)v) << 16; return x.f;
}
__device__ __forceinline__ u16 f2bf(float f) {
  union { float f; unsigned u; } x; x.f = f;
  unsigned r = x.u + 0x7FFFu + ((x.u >> 16) & 1u);
  return (u16)(r >> 16);
}
// async global->LDS, 16B per lane
__device__ __forceinline__ void g2l16(const u16* g, const u16* l) {
  __builtin_amdgcn_global_load_lds(
      (const __attribute__((address_space(1))) void*)(uintptr_t)g,
      (__attribute__((address_space(3))) void*)(uint32_t)(uintptr_t)l,
      16, 0, 0);
}

// counted vmem waits (T4): never drain to 0 in the main loop
#define SW6()  asm volatile("s_waitcnt vmcnt(6)" ::: "memory")
#define SW4()  asm volatile("s_waitcnt vmcnt(4)" ::: "memory")
#define SW3()  asm volatile("s_waitcnt vmcnt(3)" ::: "memory")
#define SW0()  asm volatile("s_waitcnt vmcnt(0)" ::: "memory")
// raw barrier + compile/IR fence (rule #18)
#define BARF()                              \
  do {                                      \
    __builtin_amdgcn_s_barrier();           \
    asm volatile("" ::: "memory");          \
    __builtin_amdgcn_sched_barrier(0);      \
  } while (0)

// ---------------- cvt: fp32 -> bf16, vectorized x4 ----------------
__global__ __launch_bounds__(256) void cvt_bf16(const float* __restrict__ s,
                                                u16* __restrict__ d, int n4) {
  int i = blockIdx.x * 256 + threadIdx.x;
  int stride = gridDim.x * 256;
  for (; i < n4; i += stride) {
    float4 v = ((const float4*)s)[i];
    u16x4 o;
    o.x = f2bf(v.x); o.y = f2bf(v.y); o.z = f2bf(v.z); o.w = f2bf(v.w);
    ((u16x4*)d)[i] = o;
  }
}

// ---------------- K0+K1 fused: LN stats + transpose + normalize ----------
__global__ __launch_bounds__(512) void ln_fused(const float* __restrict__ y,
                                                const float* __restrict__ lg,
                                                const float* __restrict__ lb,
                                                u16* __restrict__ y2c,
                                                int b0) {
  __shared__ u16 ybuf[768 * 33];          // [c][n 0..31], pitch 33 u16
  __shared__ float ps[16][32], pq[16][32];
  __shared__ float smu[32], srs[32];
  int t = threadIdx.x;
  int nl = t & 31, ch = t >> 5;           // 16 c-groups of 48
  int idx0 = b0 * N_ + blockIdx.x * 32;   // flat n-index
  int b = idx0 >> 10, nb_ = idx0 & 1023;
  const float* p = y + (size_t)b * C_ * N_ + nb_ + nl;
  float s = 0.f, q = 0.f;
  int c0 = ch * 48;
  for (int c = c0; c < c0 + 48; ++c) {
    float v = p[(size_t)c * N_];
    s += v; q += v * v;
    ybuf[c * 33 + nl] = f2bf(v);
  }
  ps[ch][nl] = s; pq[ch][nl] = q;
  __syncthreads();
  if (t < 32) {
    float ts = 0.f, tq = 0.f;
    for (int g = 0; g < 16; ++g) { ts += ps[g][t]; tq += pq[g][t]; }
    float m = ts * (1.f / C_);
    float var = tq * (1.f / C_) - m * m;
    smu[t] = m;
    srs[t] = rsqrtf(fmaxf(var, 0.f) + 1e-5f);
  }
  __syncthreads();
  int rn = t >> 4, cg = t & 15;
  float m = smu[rn], rr = srs[rn];
  int bl = b - b0;
  int n = nb_ + rn;
  u16* dst = y2c + ((size_t)bl * N_ + n) * C_ + cg * 48;
  for (int cc = 0; cc < 48; cc += 8) {
    int c = cg * 48 + cc;
    bf16x8 o;
    for (int j = 0; j < 8; ++j) {
      float v = bf2f(ybuf[(c + j) * 33 + rn]);
      o[j] = (short)f2bf((v - m) * rr * lg[c + j] + lb[c + j]);
    }
    *(bf16x8*)(dst + cc) = o;
  }
}

// ---------------- K2: merged dual-A gated GEMM, 512 threads --------------
// Same 128x128 tile / depth-3 counted-vmcnt pipeline as R5 (90us), but 8
// waves per block: each wave owns 64x32 dual-acc (64 acc regs, half of the
// 256-thr version) -> VGPR <=128 (forced via launch_bounds(512,4)) ->
// 4 waves/SIMD, 16 waves/CU at identical tile size and HBM traffic.
// Staging = 3 global_load_lds per stage (512 lanes x 16B = 8KB chunk each).
__global__ __launch_bounds__(512, 4) void gemm_gate(
    const u16* __restrict__ xbc, const u16* __restrict__ y2c,
    const u16* __restrict__ qwb, const u16* __restrict__ kvwb,
    const float* __restrict__ qb_, const float* __restrict__ kvb_,
    u16* __restrict__ o_q, u16* __restrict__ o_k, u16* __restrict__ o_vT) {
  __shared__ u16 smem[36864];  // 3 bufs x 12288 u16 (72 KiB); epilogue reuses [128][136]
  int t = threadIdx.x, l = t & 63;
  int quad = l >> 4, l15 = l & 15;
  int w = t >> 6, wm = w & 1, wn = w >> 1;   // 2 M-halves x 4 N-quarters
  int m0l = blockIdx.x * 128;
  int n0l = blockIdx.y * 128;

  const u16* wp; const float* bp; int sel, h0;
  if (n0l < C_) {
    wp = qwb + (size_t)n0l * C_; bp = qb_ + n0l; sel = 0; h0 = n0l >> 6;
  } else {
    int nk = n0l - C_;
    wp = kvwb + (size_t)nk * C_; bp = kvb_ + nk;
    sel = (nk < C_) ? 1 : 2;
    h0 = ((sel == 2) ? nk - C_ : nk) >> 6;
  }

  f4 accx[4][2], accy[4][2];
  for (int i = 0; i < 4; ++i)
    for (int j = 0; j < 2; ++j) {
      accx[i][j] = (f4){0.f, 0.f, 0.f, 0.f};
      accy[i][j] = (f4){0.f, 0.f, 0.f, 0.f};
    }

  int row = t >> 2;                          // 0..127
  int colS = (((t & 3) ^ (row & 3)) * 8);    // pre-swizzled source chunk
  const u16* gx = xbc + (size_t)(m0l + row) * C_ + colS;
  const u16* gy = y2c + (size_t)(m0l + row) * C_ + colS;
  const u16* gw = wp + (size_t)row * C_ + colS;
  int rsl = (quad ^ (l15 & 3)) * 8;          // swizzled read slot (u16)

#define STAGE_G(OFF, kk)                                   \
  do {                                                     \
    u16* p_ = smem + (OFF);                                \
    g2l16(gx + (kk), p_ + t * 8);          /* Ax 128x32 */ \
    g2l16(gy + (kk), p_ + 4096 + t * 8);   /* Ay 128x32 */ \
    g2l16(gw + (kk), p_ + 8192 + t * 8);   /* B  128x32 */ \
  } while (0)

#define COMPUTE_G(OFF)                                                        \
  do {                                                                        \
    const u16* base = smem + (OFF);                                           \
    bf16x8 bfr[2];                                                            \
    for (int j = 0; j < 2; ++j)                                               \
      bfr[j] = *(const bf16x8*)&base[8192 + (wn * 32 + j * 16 + l15) * 32 + rsl]; \
    {                                                                         \
      bf16x8 afx[4];                                                          \
      for (int i = 0; i < 4; ++i)                                             \
        afx[i] = *(const bf16x8*)&base[(wm * 64 + i * 16 + l15) * 32 + rsl];  \
      for (int i = 0; i < 4; ++i)                                             \
        for (int j = 0; j < 2; ++j)                                           \
          accx[i][j] = __builtin_amdgcn_mfma_f32_16x16x32_bf16(afx[i], bfr[j], accx[i][j], 0, 0, 0); \
    }                                                                         \
    {                                                                         \
      bf16x8 afy[4];                                                          \
      for (int i = 0; i < 4; ++i)                                             \
        afy[i] = *(const bf16x8*)&base[4096 + (wm * 64 + i * 16 + l15) * 32 + rsl]; \
      for (int i = 0; i < 4; ++i)                                             \
        for (int j = 0; j < 2; ++j)                                           \
          accy[i][j] = __builtin_amdgcn_mfma_f32_16x16x32_bf16(afy[i], bfr[j], accy[i][j], 0, 0, 0); \
    }                                                                         \
  } while (0)

#define STEP_G(i, OFF)                                        \
  do {                                                        \
    COMPUTE_G(OFF);                                           \
    BARF();                                                   \
    if ((i) < 21)      { STAGE_G(OFF, ((i) + 3) * 32); SW6(); } \
    else if ((i) == 21) SW3();                                \
    else if ((i) == 22) SW0();                                \
    BARF();                                                   \
  } while (0)

  STAGE_G(0, 0);
  STAGE_G(12288, 32);
  STAGE_G(24576, 64);
  SW6();   // tile0's 3 loads done (tiles 1,2 in flight)
  BARF();
#pragma unroll
  for (int n = 0; n < 24; n += 3) {
    STEP_G(n, 0);
    STEP_G(n + 1, 12288);
    STEP_G(n + 2, 24576);
  }
#undef STEP_G
#undef STAGE_G
#undef COMPUTE_G

  // epilogue: gate -> LDS tile [128][136] -> cached 16-B stores
  const int PITCH = 136;
  for (int j = 0; j < 2; ++j) {
    int cloc = wn * 32 + j * 16 + l15;
    float bias = bp[cloc];
    for (int i = 0; i < 4; ++i) {
      int rb0 = wm * 64 + i * 16 + quad * 4;
      for (int r = 0; r < 4; ++r) {
        int rloc = rb0 + r;
        float vx = accx[i][j][r] + bias;
        float vy = accy[i][j][r] + bias;
        float gg = 1.f / (1.f + __expf(-vy));
        float val = (sel == 0) ? vx * (1.f + gg) : gg * (vx + 1.f);
        u16 bv = f2bf(val);
        if (sel == 2) smem[cloc * PITCH + rloc] = bv;   // v staged transposed
        else          smem[rloc * PITCH + cloc] = bv;
      }
    }
  }
  __syncthreads();
  {
    int bl = m0l >> 10, nbase = m0l & 1023;
    if (sel == 2) {
      int vr = t >> 2, nq = (t & 3) * 32;      // v-dim 0..127, n-quarter
      const u16* src = smem + vr * PITCH + nq;
      int h = h0 + (vr >> 6), d = vr & 63;
      u16* dst = o_vT + (size_t)((bl * NH + h) * HD + d) * N_ + nbase + nq;
      for (int c = 0; c < 4; ++c)
        *(bf16x8*)(dst + c * 8) = *(const bf16x8*)(src + c * 8);
    } else {
      int rr = t >> 2, qc = (t & 3) * 32;      // row 0..127, col-quarter
      const u16* src = smem + rr * PITCH + qc;
      int gml = m0l + rr;
      int bl2 = gml >> 10, n = gml & 1023;
      int h = h0 + (qc >> 6), d0 = qc & 63;
      u16* dst = (sel == 0 ? o_q : o_k) +
                 (size_t)((bl2 * NH + h) * N_ + n) * HD + d0;
      for (int c = 0; c < 4; ++c)
        *(bf16x8*)(dst + c * 8) = *(const bf16x8*)(src + c * 8);
    }
  }
}

// ---------------- K3: fused attention (R9-exact) -------------------------
__global__ __launch_bounds__(256) void attn(const u16* __restrict__ qoc,
                                            const u16* __restrict__ koc,
                                            const u16* __restrict__ vTc,
                                            u16* __restrict__ aoc) {
  __shared__ u16 Qs[4096], Ks[8192], Vs[8192];
  __shared__ u16 Ps[64 * 72];
  int t = threadIdx.x, l = t & 63, w = t >> 6;
  int quad = l >> 4, l15 = l & 15;
  int bhl = blockIdx.y;
  int bl = bhl / NH, h = bhl % NH;
  int q0 = blockIdx.x * 64;
  int sr = t >> 3;                       // staging row (0..31, +32 second half)
  int swo = ((t & 7) ^ (sr & 7)) * 8;    // swizzled source chunk offset (u16)
  const u16* qbp = qoc + ((size_t)bhl * N_ + q0) * HD;
  const u16* kb = koc + (size_t)bhl * N_ * HD;
  const u16* vb = vTc + (size_t)bhl * HD * N_;

#define STAGE_KV(OFF, key0)                                                   \
  do {                                                                        \
    g2l16(kb + (size_t)((key0) + sr) * HD + swo,      Ks + (OFF) + t * 8);    \
    g2l16(kb + (size_t)((key0) + 32 + sr) * HD + swo, Ks + (OFF) + 2048 + t * 8); \
    g2l16(vb + (size_t)sr * N_ + (key0) + swo,        Vs + (OFF) + t * 8);    \
    g2l16(vb + (size_t)(32 + sr) * N_ + (key0) + swo, Vs + (OFF) + 2048 + t * 8); \
  } while (0)

  g2l16(qbp + sr * HD + swo,        Qs + t * 8);
  g2l16(qbp + (32 + sr) * HD + swo, Qs + 2048 + t * 8);
  STAGE_KV(0, 0);
  STAGE_KV(4096, 64);
  SW4();   // Q(2) + KV0(4) done; KV1's 4 in flight
  BARF();

  int sA = (quad ^ (l15 & 7)) * 8;  // swizzled slot, contraction chunks 0-3
  int sB = sA ^ 32;                 // chunks 4-7
  bf16x8 aq0 = *(const bf16x8*)&Qs[(w * 16 + l15) * 64 + sA];
  bf16x8 aq1 = *(const bf16x8*)&Qs[(w * 16 + l15) * 64 + sB];
  f4 o[4];
  for (int i = 0; i < 4; ++i) o[i] = (f4){0.f, 0.f, 0.f, 0.f};
  f4 ls = (f4){0.f, 0.f, 0.f, 0.f};
  bf16x8 ones;
  for (int i = 0; i < 8; ++i) ones[i] = (short)0x3F80;  // bf16 1.0

#define TILE_STEP(KOFF)                                                       \
  do {                                                                        \
    f4 s_[4];                                                                 \
    __builtin_amdgcn_s_setprio(1);                                            \
    for (int ni = 0; ni < 4; ++ni) {                                          \
      bf16x8 b0v = *(const bf16x8*)&Ks[(KOFF) + (ni * 16 + l15) * 64 + sA];   \
      bf16x8 b1v = *(const bf16x8*)&Ks[(KOFF) + (ni * 16 + l15) * 64 + sB];   \
      f4 z = (f4){0.f, 0.f, 0.f, 0.f};                                        \
      z = __builtin_amdgcn_mfma_f32_16x16x32_bf16(aq0, b0v, z, 0, 0, 0);      \
      z = __builtin_amdgcn_mfma_f32_16x16x32_bf16(aq1, b1v, z, 0, 0, 0);      \
      s_[ni] = z;                                                             \
    }                                                                         \
    __builtin_amdgcn_s_setprio(0);                                            \
    for (int ni = 0; ni < 4; ++ni)                                            \
      for (int r = 0; r < 4; ++r)                                             \
        Ps[(w * 16 + quad * 4 + r) * 72 + ni * 16 + l15] =                    \
            f2bf(__expf(s_[ni][r] * 0.125f));                                 \
    bf16x8 ap0 = *(const bf16x8*)&Ps[(w * 16 + l15) * 72 + quad * 8];         \
    bf16x8 ap1 = *(const bf16x8*)&Ps[(w * 16 + l15) * 72 + 32 + quad * 8];    \
    __builtin_amdgcn_s_setprio(1);                                            \
    for (int ni = 0; ni < 4; ++ni) {                                          \
      bf16x8 b0v = *(const bf16x8*)&Vs[(KOFF) + (ni * 16 + l15) * 64 + sA];   \
      bf16x8 b1v = *(const bf16x8*)&Vs[(KOFF) + (ni * 16 + l15) * 64 + sB];   \
      o[ni] = __builtin_amdgcn_mfma_f32_16x16x32_bf16(ap0, b0v, o[ni], 0, 0, 0); \
      o[ni] = __builtin_amdgcn_mfma_f32_16x16x32_bf16(ap1, b1v, o[ni], 0, 0, 0); \
    }                                                                         \
    ls = __builtin_amdgcn_mfma_f32_16x16x32_bf16(ap0, ones, ls, 0, 0, 0);     \
    ls = __builtin_amdgcn_mfma_f32_16x16x32_bf16(ap1, ones, ls, 0, 0, 0);     \
    __builtin_amdgcn_s_setprio(0);                                            \
  } while (0)

  for (int kt = 0; kt < 16; kt += 2) {
    TILE_STEP(0);
    BARF();                                   // done reading KV half 0
    if (kt + 2 < 16) { STAGE_KV(0, (kt + 2) * 64); SW4(); } else { SW0(); }
    BARF();                                   // KV half 1 visible
    TILE_STEP(4096);
    BARF();                                   // done reading KV half 1
    if (kt + 3 < 16) { STAGE_KV(4096, (kt + 3) * 64); SW4(); } else { SW0(); }
    BARF();                                   // KV half 0 visible
  }
#undef TILE_STEP
#undef STAGE_KV

  for (int ni = 0; ni < 4; ++ni)
    for (int r = 0; r < 4; ++r)
      Ps[(w * 16 + quad * 4 + r) * 72 + ni * 16 + l15] =
          f2bf(o[ni][r] / ls[r]);
  __syncthreads();
  {
    int rr = t >> 2, cc = t & 3;
    int n = q0 + rr;
    const u16* src = Ps + rr * 72 + cc * 16;
    u16* dst = aoc + ((size_t)bl * N_ + n) * C_ + h * HD + cc * 16;
    *(bf16x8*)dst = *(const bf16x8*)src;
    *(bf16x8*)(dst + 8) = *(const bf16x8*)(src + 8);
  }
}

// ---------------- K4: output projection GEMM (R9-exact) ------------------
__global__ __launch_bounds__(256, 2) void gemm_proj(const u16* __restrict__ aoc,
                                                    const u16* __restrict__ pwb,
                                                    const float* __restrict__ bias,
                                                    float* __restrict__ out,
                                                    int b0) {
  __shared__ u16 smem[12288];  // 2 bufs x (A 4096 + B 2048)
  int t = threadIdx.x, l = t & 63;
  int quad = l >> 4, l15 = l & 15;
  int w = t >> 6, wm = w & 1, wn = w >> 1;
  int m0l = blockIdx.x * 128, n0 = blockIdx.y * 64;
  f4 acc[4][2];
  for (int i = 0; i < 4; ++i)
    for (int j = 0; j < 2; ++j) acc[i][j] = (f4){0.f, 0.f, 0.f, 0.f};
  int row = t >> 2, colb = (t & 3) * 8;
  const u16* ga = aoc + (size_t)(m0l + row) * C_ + colb;
  const u16* gw = pwb + (size_t)(n0 + row) * C_ + colb;

#define STAGE_P(OFF, kk)                                   \
  do {                                                     \
    u16* p_ = smem + (OFF);                                \
    g2l16(ga + (kk),           p_ + t * 8);                \
    g2l16(ga + (kk) + 64 * C_, p_ + 2048 + t * 8);         \
    g2l16(gw + (kk),           p_ + 4096 + t * 8);         \
  } while (0)

#define COMPUTE_P(OFF)                                                        \
  do {                                                                        \
    const u16* base = smem + (OFF);                                           \
    bf16x8 af[4], bfr[2];                                                     \
    for (int i = 0; i < 4; ++i)                                               \
      af[i] = *(const bf16x8*)&base[(wm * 64 + i * 16 + l15) * 32 + quad * 8];\
    for (int j = 0; j < 2; ++j)                                               \
      bfr[j] = *(const bf16x8*)&base[4096 + (wn * 32 + j * 16 + l15) * 32 + quad * 8]; \
    for (int i = 0; i < 4; ++i)                                               \
      for (int j = 0; j < 2; ++j)                                             \
        acc[i][j] = __builtin_amdgcn_mfma_f32_16x16x32_bf16(af[i], bfr[j], acc[i][j], 0, 0, 0); \
  } while (0)

  STAGE_P(0, 0);
  STAGE_P(6144, 32);
  SW3();
  BARF();
  for (int n = 0; n < 24; n += 2) {
    COMPUTE_P(0);
    BARF();
    if (n + 2 < 24) { STAGE_P(0, (n + 2) * 32); SW3(); } else { SW0(); }
    BARF();
    COMPUTE_P(6144);
    BARF();
    if (n + 3 < 24) { STAGE_P(6144, (n + 3) * 32); SW3(); } else { SW0(); }
    BARF();
  }
#undef STAGE_P
#undef COMPUTE_P

  for (int j = 0; j < 2; ++j) {
    int gcol = n0 + wn * 32 + j * 16 + l15;
    float bv = bias[gcol];
    for (int i = 0; i < 4; ++i) {
      int rbase = m0l + wm * 64 + i * 16 + quad * 4;
      for (int r = 0; r < 4; ++r)
        __builtin_nontemporal_store(acc[i][j][r] + bv,
                                    &out[(size_t)(b0 * N_ + rbase + r) * C_ + gcol]);
    }
  }
}

extern "C" void kernel_launch(void* const* d_in, const int* in_sizes, int n_in,
                              void* d_out, int out_size, void* d_ws, size_t ws_size,
                              hipStream_t stream) {
  const float* x   = (const float*)d_in[0];
  const float* y   = (const float*)d_in[1];
  const float* qw  = (const float*)d_in[2];
  const float* qb  = (const float*)d_in[3];
  const float* kvw = (const float*)d_in[4];
  const float* kvb = (const float*)d_in[5];
  const float* pw  = (const float*)d_in[6];
  const float* pb  = (const float*)d_in[7];
  const float* lg  = (const float*)d_in[8];
  const float* lb  = (const float*)d_in[9];

  char* ws = (char*)d_ws;
  u16* qwb  = (u16*)(ws + 65536);
  u16* kvwb = (u16*)(ws + 1245184);
  u16* pwb  = (u16*)(ws + 3604480);
  const size_t BASE2 = 4784128;
  const size_t PER_B = 1572864;

  int nb = 1;
  for (int c = 8; c >= 1; c >>= 1) {
    if (BASE2 + 5 * (size_t)c * PER_B <= ws_size) { nb = c; break; }
  }
  u16* xbc = (u16*)(ws + BASE2);
  u16* y2c = (u16*)(ws + BASE2 + (size_t)nb * PER_B);
  u16* qoc = (u16*)(ws + BASE2 + 2 * (size_t)nb * PER_B);
  u16* koc = (u16*)(ws + BASE2 + 3 * (size_t)nb * PER_B);
  u16* vTc = (u16*)(ws + BASE2 + 4 * (size_t)nb * PER_B);
  u16* aoc = xbc;

  cvt_bf16<<<dim3(576), dim3(256), 0, stream>>>(qw, qwb, 147456);
  cvt_bf16<<<dim3(1152), dim3(256), 0, stream>>>(kvw, kvwb, 294912);
  cvt_bf16<<<dim3(576), dim3(256), 0, stream>>>(pw, pwb, 147456);

  for (int b0 = 0; b0 < B_; b0 += nb) {
    cvt_bf16<<<dim3(768 * nb), dim3(256), 0, stream>>>(
        x + (size_t)b0 * N_ * C_, xbc, nb * 196608);
    ln_fused<<<dim3(32 * nb), dim3(512), 0, stream>>>(y, lg, lb, y2c, b0);
    gemm_gate<<<dim3(8 * nb, 18), dim3(512), 0, stream>>>(xbc, y2c, qwb, kvwb,
                                                          qb, kvb, qoc, koc, vTc);
    attn<<<dim3(16, 12 * nb), dim3(256), 0, stream>>>(qoc, koc, vTc, aoc);
    gemm_proj<<<dim3(8 * nb, 12), dim3(256), 0, stream>>>(aoc, pwb, pb, (float*)d_out, b0);
  }
}

// Round 11
// 268.170 us; speedup vs baseline: 1.1230x; 1.0084x over previous
//
#include <hip/hip_runtime.h>
#include <stdint.h>

typedef __attribute__((ext_vector_type(4))) float f4;
typedef __attribute__((ext_vector_type(8))) short bf16x8;
typedef __attribute__((ext_vector_type(4))) unsigned short u16x4;
typedef unsigned short u16;

#define B_ 8
#define N_ 1024
#define C_ 768
#define NH 12
#define HD 64

__device__ __forceinline__ float bf2f(u16 v) {
  union { unsigned u; float f; } x; x.u = ((unsigned)v) << 16; return x.f;
}
__device__ __forceinline__ u16 f2bf(float f) {
  union { float f; unsigned u; } x; x.f = f;
  unsigned r = x.u + 0x7FFFu + ((x.u >> 16) & 1u);
  return (u16)(r >> 16);
}
// async global->LDS, 16B per lane
__device__ __forceinline__ void g2l16(const u16* g, const u16* l) {
  __builtin_amdgcn_global_load_lds(
      (const __attribute__((address_space(1))) void*)(uintptr_t)g,
      (__attribute__((address_space(3))) void*)(uint32_t)(uintptr_t)l,
      16, 0, 0);
}

// counted vmem waits (T4): never drain to 0 in the main loop
#define SW12() asm volatile("s_waitcnt vmcnt(12)" ::: "memory")
#define SW6()  asm volatile("s_waitcnt vmcnt(6)" ::: "memory")
#define SW4()  asm volatile("s_waitcnt vmcnt(4)" ::: "memory")
#define SW3()  asm volatile("s_waitcnt vmcnt(3)" ::: "memory")
#define SW2()  asm volatile("s_waitcnt vmcnt(2)" ::: "memory")
#define SW0()  asm volatile("s_waitcnt vmcnt(0)" ::: "memory")
// raw barrier + compile/IR fence (rule #18)
#define BARF()                              \
  do {                                      \
    __builtin_amdgcn_s_barrier();           \
    asm volatile("" ::: "memory");          \
    __builtin_amdgcn_sched_barrier(0);      \
  } while (0)

// ---------------- cvt: fp32 -> bf16, vectorized x4 ----------------
__global__ __launch_bounds__(256) void cvt_bf16(const float* __restrict__ s,
                                                u16* __restrict__ d, int n4) {
  int i = blockIdx.x * 256 + threadIdx.x;
  int stride = gridDim.x * 256;
  for (; i < n4; i += stride) {
    float4 v = ((const float4*)s)[i];
    u16x4 o;
    o.x = f2bf(v.x); o.y = f2bf(v.y); o.z = f2bf(v.z); o.w = f2bf(v.w);
    ((u16x4*)d)[i] = o;
  }
}

// ---------------- K0+K1 fused: LN stats + transpose + normalize ----------
__global__ __launch_bounds__(512) void ln_fused(const float* __restrict__ y,
                                                const float* __restrict__ lg,
                                                const float* __restrict__ lb,
                                                u16* __restrict__ y2c,
                                                int b0) {
  __shared__ u16 ybuf[768 * 33];          // [c][n 0..31], pitch 33 u16
  __shared__ float ps[16][32], pq[16][32];
  __shared__ float smu[32], srs[32];
  int t = threadIdx.x;
  int nl = t & 31, ch = t >> 5;           // 16 c-groups of 48
  int idx0 = b0 * N_ + blockIdx.x * 32;   // flat n-index
  int b = idx0 >> 10, nb_ = idx0 & 1023;
  const float* p = y + (size_t)b * C_ * N_ + nb_ + nl;
  float s = 0.f, q = 0.f;
  int c0 = ch * 48;
  for (int c = c0; c < c0 + 48; ++c) {
    float v = p[(size_t)c * N_];
    s += v; q += v * v;
    ybuf[c * 33 + nl] = f2bf(v);
  }
  ps[ch][nl] = s; pq[ch][nl] = q;
  __syncthreads();
  if (t < 32) {
    float ts = 0.f, tq = 0.f;
    for (int g = 0; g < 16; ++g) { ts += ps[g][t]; tq += pq[g][t]; }
    float m = ts * (1.f / C_);
    float var = tq * (1.f / C_) - m * m;
    smu[t] = m;
    srs[t] = rsqrtf(fmaxf(var, 0.f) + 1e-5f);
  }
  __syncthreads();
  int rn = t >> 4, cg = t & 15;
  float m = smu[rn], rr = srs[rn];
  int bl = b - b0;
  int n = nb_ + rn;
  u16* dst = y2c + ((size_t)bl * N_ + n) * C_ + cg * 48;
  for (int cc = 0; cc < 48; cc += 8) {
    int c = cg * 48 + cc;
    bf16x8 o;
    for (int j = 0; j < 8; ++j) {
      float v = bf2f(ybuf[(c + j) * 33 + rn]);
      o[j] = (short)f2bf((v - m) * rr * lg[c + j] + lb[c + j]);
    }
    *(bf16x8*)(dst + cc) = o;
  }
}

// ---------------- K2: merged dual-A gated GEMM (R5-exact, best: 90us) ----
// Depth-3 pipeline, counted vmcnt(12), XOR-swizzled LDS, 128x128 tiles.
__global__ __launch_bounds__(256, 2) void gemm_gate(
    const u16* __restrict__ xbc, const u16* __restrict__ y2c,
    const u16* __restrict__ qwb, const u16* __restrict__ kvwb,
    const float* __restrict__ qb_, const float* __restrict__ kvb_,
    u16* __restrict__ o_q, u16* __restrict__ o_k, u16* __restrict__ o_vT) {
  __shared__ u16 smem[36864];  // 3 bufs x 12288 u16 (72 KiB); epilogue reuses front
  int t = threadIdx.x, l = t & 63;
  int quad = l >> 4, l15 = l & 15;
  int w = t >> 6, wm = w & 1, wn = w >> 1;
  int m0l = blockIdx.x * 128;
  int n0l = blockIdx.y * 128;

  const u16* wp; const float* bp; int sel, h0;
  if (n0l < C_) {
    wp = qwb + (size_t)n0l * C_; bp = qb_ + n0l; sel = 0; h0 = n0l >> 6;
  } else {
    int nk = n0l - C_;
    wp = kvwb + (size_t)nk * C_; bp = kvb_ + nk;
    sel = (nk < C_) ? 1 : 2;
    h0 = ((sel == 2) ? nk - C_ : nk) >> 6;
  }

  f4 accx[4][4], accy[4][4];
  for (int i = 0; i < 4; ++i)
    for (int j = 0; j < 4; ++j) {
      accx[i][j] = (f4){0.f, 0.f, 0.f, 0.f};
      accy[i][j] = (f4){0.f, 0.f, 0.f, 0.f};
    }

  int row = t >> 2;
  int colS = (((t & 3) ^ (row & 3)) * 8);   // pre-swizzled source chunk
  const u16* gx = xbc + (size_t)(m0l + row) * C_ + colS;
  const u16* gy = y2c + (size_t)(m0l + row) * C_ + colS;
  const u16* gw = wp + (size_t)row * C_ + colS;
  int rsl = (quad ^ (l15 & 3)) * 8;         // swizzled read slot (u16)

#define STAGE_G(OFF, kk)                                   \
  do {                                                     \
    u16* p_ = smem + (OFF);                                \
    g2l16(gx + (kk),           p_ + t * 8);                \
    g2l16(gx + (kk) + 64 * C_, p_ + 2048 + t * 8);         \
    g2l16(gy + (kk),           p_ + 4096 + t * 8);         \
    g2l16(gy + (kk) + 64 * C_, p_ + 6144 + t * 8);         \
    g2l16(gw + (kk),           p_ + 8192 + t * 8);         \
    g2l16(gw + (kk) + 64 * C_, p_ + 10240 + t * 8);        \
  } while (0)

#define COMPUTE_G(OFF)                                                        \
  do {                                                                        \
    const u16* base = smem + (OFF);                                           \
    bf16x8 afx[4], afy[4], bfr[4];                                            \
    for (int i = 0; i < 4; ++i) {                                             \
      int ra = (wm * 64 + i * 16 + l15) * 32 + rsl;                           \
      afx[i] = *(const bf16x8*)&base[ra];                                     \
      afy[i] = *(const bf16x8*)&base[4096 + ra];                              \
      int rb = (wn * 64 + i * 16 + l15) * 32 + rsl;                           \
      bfr[i] = *(const bf16x8*)&base[8192 + rb];                              \
    }                                                                         \
    for (int i = 0; i < 4; ++i)                                               \
      for (int j = 0; j < 4; ++j) {                                           \
        accx[i][j] = __builtin_amdgcn_mfma_f32_16x16x32_bf16(afx[i], bfr[j], accx[i][j], 0, 0, 0); \
        accy[i][j] = __builtin_amdgcn_mfma_f32_16x16x32_bf16(afy[i], bfr[j], accy[i][j], 0, 0, 0); \
      }                                                                       \
  } while (0)

#define STEP_G(i, OFF)                                        \
  do {                                                        \
    COMPUTE_G(OFF);                                           \
    BARF();                                                   \
    if ((i) < 21)      { STAGE_G(OFF, ((i) + 3) * 32); SW12(); } \
    else if ((i) == 21) SW6();                                \
    else if ((i) == 22) SW0();                                \
    BARF();                                                   \
  } while (0)

  STAGE_G(0, 0);
  STAGE_G(12288, 32);
  STAGE_G(24576, 64);
  SW12();   // tile0 done (tiles 1,2 in flight)
  BARF();
#pragma unroll
  for (int n = 0; n < 24; n += 3) {
    STEP_G(n, 0);
    STEP_G(n + 1, 12288);
    STEP_G(n + 2, 24576);
  }
#undef STEP_G
#undef STAGE_G
#undef COMPUTE_G

  // epilogue: gate -> LDS tile -> cached 16-B stores
  const int PITCH = 136;
  for (int j = 0; j < 4; ++j) {
    int cloc = wn * 64 + j * 16 + l15;
    float bias = bp[cloc];
    for (int i = 0; i < 4; ++i) {
      int rb0 = wm * 64 + i * 16 + quad * 4;
      for (int r = 0; r < 4; ++r) {
        int rloc = rb0 + r;
        float vx = accx[i][j][r] + bias;
        float vy = accy[i][j][r] + bias;
        float gg = 1.f / (1.f + __expf(-vy));
        float val = (sel == 0) ? vx * (1.f + gg) : gg * (vx + 1.f);
        u16 bv = f2bf(val);
        if (sel == 2) smem[cloc * PITCH + rloc] = bv;   // v staged transposed
        else          smem[rloc * PITCH + cloc] = bv;
      }
    }
  }
  __syncthreads();
  {
    int rr = t >> 1, hh = t & 1;
    const u16* src = smem + rr * PITCH + hh * 64;
    u16* dst;
    if (sel == 2) {
      int h = h0 + (rr >> 6), d = rr & 63;
      int bl = m0l >> 10, nbase = m0l & 1023;
      dst = o_vT + (size_t)((bl * NH + h) * HD + d) * N_ + nbase + hh * 64;
    } else {
      int gml = m0l + rr;
      int bl = gml >> 10, n = gml & 1023;
      int h = h0 + hh;
      dst = (sel == 0 ? o_q : o_k) + (size_t)((bl * NH + h) * N_ + n) * HD;
    }
    for (int c = 0; c < 8; ++c) {
      bf16x8 v = *(const bf16x8*)(src + c * 8);
      *(bf16x8*)(dst + c * 8) = v;
    }
  }
}

// ---------------- K3: fused attention, Q-tile 128, 512 threads -----------
// 8 waves, each owns ONE 16-q-row group (avoids R8's serial dual-group).
// K/V staged once per 128 q-rows (half the traffic/barriers of Q64);
// one global_load_lds per K/V half-tile (512 lanes x 16B = 8KB).
__global__ __launch_bounds__(512) void attn(const u16* __restrict__ qoc,
                                            const u16* __restrict__ koc,
                                            const u16* __restrict__ vTc,
                                            u16* __restrict__ aoc) {
  __shared__ u16 Qs[8192], Ks[8192], Vs[8192];   // Q 128x64; K/V 2 half-tiles
  __shared__ u16 Ps[128 * 72];
  int t = threadIdx.x, l = t & 63, w = t >> 6;   // w: 0..7
  int quad = l >> 4, l15 = l & 15;
  int bhl = blockIdx.y;
  int bl = bhl / NH, h = bhl % NH;
  int q0 = blockIdx.x * 128;
  int sr = t >> 3;                       // staging row 0..63
  int swo = ((t & 7) ^ (sr & 7)) * 8;    // swizzled source chunk offset (u16)
  const u16* qbp = qoc + ((size_t)bhl * N_ + q0) * HD;
  const u16* kb = koc + (size_t)bhl * N_ * HD;
  const u16* vb = vTc + (size_t)bhl * HD * N_;

#define STAGE_KV(OFF, key0)                                                \
  do {                                                                     \
    g2l16(kb + (size_t)((key0) + sr) * HD + swo, Ks + (OFF) + t * 8);      \
    g2l16(vb + (size_t)sr * N_ + (key0) + swo,   Vs + (OFF) + t * 8);      \
  } while (0)

  g2l16(qbp + (size_t)sr * HD + swo,        Qs + t * 8);
  g2l16(qbp + (size_t)(64 + sr) * HD + swo, Qs + 4096 + t * 8);
  STAGE_KV(0, 0);
  STAGE_KV(4096, 64);
  SW2();   // Q(2) + KV0(2) done; KV1's 2 in flight
  BARF();

  int sA = (quad ^ (l15 & 7)) * 8;  // swizzled slot, contraction chunks 0-3
  int sB = sA ^ 32;                 // chunks 4-7
  bf16x8 aq0 = *(const bf16x8*)&Qs[(w * 16 + l15) * 64 + sA];
  bf16x8 aq1 = *(const bf16x8*)&Qs[(w * 16 + l15) * 64 + sB];
  f4 o[4];
  for (int i = 0; i < 4; ++i) o[i] = (f4){0.f, 0.f, 0.f, 0.f};
  f4 ls = (f4){0.f, 0.f, 0.f, 0.f};
  bf16x8 ones;
  for (int i = 0; i < 8; ++i) ones[i] = (short)0x3F80;  // bf16 1.0

#define TILE_STEP(KOFF)                                                       \
  do {                                                                        \
    f4 s_[4];                                                                 \
    __builtin_amdgcn_s_setprio(1);                                            \
    for (int ni = 0; ni < 4; ++ni) {                                          \
      bf16x8 b0v = *(const bf16x8*)&Ks[(KOFF) + (ni * 16 + l15) * 64 + sA];   \
      bf16x8 b1v = *(const bf16x8*)&Ks[(KOFF) + (ni * 16 + l15) * 64 + sB];   \
      f4 z = (f4){0.f, 0.f, 0.f, 0.f};                                        \
      z = __builtin_amdgcn_mfma_f32_16x16x32_bf16(aq0, b0v, z, 0, 0, 0);      \
      z = __builtin_amdgcn_mfma_f32_16x16x32_bf16(aq1, b1v, z, 0, 0, 0);      \
      s_[ni] = z;                                                             \
    }                                                                         \
    __builtin_amdgcn_s_setprio(0);                                            \
    for (int ni = 0; ni < 4; ++ni)                                            \
      for (int r = 0; r < 4; ++r)                                             \
        Ps[(w * 16 + quad * 4 + r) * 72 + ni * 16 + l15] =                    \
            f2bf(__expf(s_[ni][r] * 0.125f));                                 \
    bf16x8 ap0 = *(const bf16x8*)&Ps[(w * 16 + l15) * 72 + quad * 8];         \
    bf16x8 ap1 = *(const bf16x8*)&Ps[(w * 16 + l15) * 72 + 32 + quad * 8];    \
    __builtin_amdgcn_s_setprio(1);                                            \
    for (int ni = 0; ni < 4; ++ni) {                                          \
      bf16x8 b0v = *(const bf16x8*)&Vs[(KOFF) + (ni * 16 + l15) * 64 + sA];   \
      bf16x8 b1v = *(const bf16x8*)&Vs[(KOFF) + (ni * 16 + l15) * 64 + sB];   \
      o[ni] = __builtin_amdgcn_mfma_f32_16x16x32_bf16(ap0, b0v, o[ni], 0, 0, 0); \
      o[ni] = __builtin_amdgcn_mfma_f32_16x16x32_bf16(ap1, b1v, o[ni], 0, 0, 0); \
    }                                                                         \
    ls = __builtin_amdgcn_mfma_f32_16x16x32_bf16(ap0, ones, ls, 0, 0, 0);     \
    ls = __builtin_amdgcn_mfma_f32_16x16x32_bf16(ap1, ones, ls, 0, 0, 0);     \
    __builtin_amdgcn_s_setprio(0);                                            \
  } while (0)

  for (int kt = 0; kt < 16; kt += 2) {
    TILE_STEP(0);
    BARF();                                   // done reading KV half 0
    if (kt + 2 < 16) { STAGE_KV(0, (kt + 2) * 64); SW2(); } else { SW0(); }
    BARF();                                   // KV half 1 visible
    TILE_STEP(4096);
    BARF();                                   // done reading KV half 1
    if (kt + 3 < 16) { STAGE_KV(4096, (kt + 3) * 64); SW2(); } else { SW0(); }
    BARF();                                   // KV half 0 visible
  }
#undef TILE_STEP
#undef STAGE_KV

  for (int ni = 0; ni < 4; ++ni)
    for (int r = 0; r < 4; ++r)
      Ps[(w * 16 + quad * 4 + r) * 72 + ni * 16 + l15] =
          f2bf(o[ni][r] / ls[r]);
  __syncthreads();
  {
    int rr = t >> 2, cc = t & 3;               // 128 rows x 4 chunks of 16
    int n = q0 + rr;
    const u16* src = Ps + rr * 72 + cc * 16;
    u16* dst = aoc + ((size_t)bl * N_ + n) * C_ + h * HD + cc * 16;
    *(bf16x8*)dst = *(const bf16x8*)src;
    *(bf16x8*)(dst + 8) = *(const bf16x8*)(src + 8);
  }
}

// ---------------- K4: output projection GEMM, BK=64 depth-2 --------------
// 12 K-steps (was 24), 16 MFMA/wave/step, 48KB LDS -> 3 blocks/CU.
__global__ __launch_bounds__(256, 2) void gemm_proj(const u16* __restrict__ aoc,
                                                    const u16* __restrict__ pwb,
                                                    const float* __restrict__ bias,
                                                    float* __restrict__ out,
                                                    int b0) {
  __shared__ u16 smem[24576];  // 2 bufs x 12288 (A 128x64 + B 64x64)
  int t = threadIdx.x, l = t & 63;
  int quad = l >> 4, l15 = l & 15;
  int w = t >> 6, wm = w & 1, wn = w >> 1;
  int m0l = blockIdx.x * 128, n0 = blockIdx.y * 64;
  f4 acc[4][2];
  for (int i = 0; i < 4; ++i)
    for (int j = 0; j < 2; ++j) acc[i][j] = (f4){0.f, 0.f, 0.f, 0.f};
  int row = t >> 2, colb = (t & 3) * 8;
  const u16* ga = aoc + (size_t)(m0l + row) * C_ + colb;
  const u16* gw = pwb + (size_t)(n0 + row) * C_ + colb;

#define STAGE_P(OFF, kk)                                        \
  do {                                                          \
    u16* p_ = smem + (OFF);                                     \
    g2l16(ga + (kk),                p_ + t * 8);                \
    g2l16(ga + (kk) + 64 * C_,      p_ + 2048 + t * 8);         \
    g2l16(ga + (kk) + 32,           p_ + 4096 + t * 8);         \
    g2l16(ga + (kk) + 32 + 64 * C_, p_ + 6144 + t * 8);         \
    g2l16(gw + (kk),                p_ + 8192 + t * 8);         \
    g2l16(gw + (kk) + 32,           p_ + 10240 + t * 8);        \
  } while (0)

#define COMPUTE_P(OFF)                                                        \
  do {                                                                        \
    const u16* base = smem + (OFF);                                           \
    _Pragma("unroll")                                                         \
    for (int kh = 0; kh < 2; ++kh) {                                          \
      bf16x8 af[4], bfr[2];                                                   \
      for (int i = 0; i < 4; ++i)                                             \
        af[i] = *(const bf16x8*)&base[kh * 4096 + (wm * 64 + i * 16 + l15) * 32 + quad * 8]; \
      for (int j = 0; j < 2; ++j)                                             \
        bfr[j] = *(const bf16x8*)&base[8192 + kh * 2048 + (wn * 32 + j * 16 + l15) * 32 + quad * 8]; \
      for (int i = 0; i < 4; ++i)                                             \
        for (int j = 0; j < 2; ++j)                                           \
          acc[i][j] = __builtin_amdgcn_mfma_f32_16x16x32_bf16(af[i], bfr[j], acc[i][j], 0, 0, 0); \
    }                                                                         \
  } while (0)

  STAGE_P(0, 0);
  STAGE_P(12288, 64);
  SW6();
  BARF();
  for (int n = 0; n < 12; n += 2) {
    COMPUTE_P(0);
    BARF();
    if (n + 2 < 12) { STAGE_P(0, (n + 2) * 64); SW6(); } else { SW0(); }
    BARF();
    COMPUTE_P(12288);
    BARF();
    if (n + 3 < 12) { STAGE_P(12288, (n + 3) * 64); SW6(); } else { SW0(); }
    BARF();
  }
#undef STAGE_P
#undef COMPUTE_P

  for (int j = 0; j < 2; ++j) {
    int gcol = n0 + wn * 32 + j * 16 + l15;
    float bv = bias[gcol];
    for (int i = 0; i < 4; ++i) {
      int rbase = m0l + wm * 64 + i * 16 + quad * 4;
      for (int r = 0; r < 4; ++r)
        __builtin_nontemporal_store(acc[i][j][r] + bv,
                                    &out[(size_t)(b0 * N_ + rbase + r) * C_ + gcol]);
    }
  }
}

extern "C" void kernel_launch(void* const* d_in, const int* in_sizes, int n_in,
                              void* d_out, int out_size, void* d_ws, size_t ws_size,
                              hipStream_t stream) {
  const float* x   = (const float*)d_in[0];
  const float* y   = (const float*)d_in[1];
  const float* qw  = (const float*)d_in[2];
  const float* qb  = (const float*)d_in[3];
  const float* kvw = (const float*)d_in[4];
  const float* kvb = (const float*)d_in[5];
  const float* pw  = (const float*)d_in[6];
  const float* pb  = (const float*)d_in[7];
  const float* lg  = (const float*)d_in[8];
  const float* lb  = (const float*)d_in[9];

  char* ws = (char*)d_ws;
  u16* qwb  = (u16*)(ws + 65536);
  u16* kvwb = (u16*)(ws + 1245184);
  u16* pwb  = (u16*)(ws + 3604480);
  const size_t BASE2 = 4784128;
  const size_t PER_B = 1572864;

  int nb = 1;
  for (int c = 8; c >= 1; c >>= 1) {
    if (BASE2 + 5 * (size_t)c * PER_B <= ws_size) { nb = c; break; }
  }
  u16* xbc = (u16*)(ws + BASE2);
  u16* y2c = (u16*)(ws + BASE2 + (size_t)nb * PER_B);
  u16* qoc = (u16*)(ws + BASE2 + 2 * (size_t)nb * PER_B);
  u16* koc = (u16*)(ws + BASE2 + 3 * (size_t)nb * PER_B);
  u16* vTc = (u16*)(ws + BASE2 + 4 * (size_t)nb * PER_B);
  u16* aoc = xbc;

  cvt_bf16<<<dim3(576), dim3(256), 0, stream>>>(qw, qwb, 147456);
  cvt_bf16<<<dim3(1152), dim3(256), 0, stream>>>(kvw, kvwb, 294912);
  cvt_bf16<<<dim3(576), dim3(256), 0, stream>>>(pw, pwb, 147456);

  for (int b0 = 0; b0 < B_; b0 += nb) {
    cvt_bf16<<<dim3(768 * nb), dim3(256), 0, stream>>>(
        x + (size_t)b0 * N_ * C_, xbc, nb * 196608);
    ln_fused<<<dim3(32 * nb), dim3(512), 0, stream>>>(y, lg, lb, y2c, b0);
    gemm_gate<<<dim3(8 * nb, 18), dim3(256), 0, stream>>>(xbc, y2c, qwb, kvwb,
                                                          qb, kvb, qoc, koc, vTc);
    attn<<<dim3(8, 12 * nb), dim3(512), 0, stream>>>(qoc, koc, vTc, aoc);
    gemm_proj<<<dim3(8 * nb, 12), dim3(256), 0, stream>>>(aoc, pwb, pb, (float*)d_out, b0);
  }
}